// Round 14
// baseline (707.440 us; speedup 1.0000x reference)
//
#include <hip/hip_runtime.h>
#include <math.h>

#define N_SP 65536   // h*w
#define IMG  256

typedef __attribute__((ext_vector_type(8))) short s16x8;
typedef __attribute__((ext_vector_type(4))) float f32x4;

// RNE fp32->bf16 (bit version, deterministic) and back
__device__ inline ushort f2bf(float f) {
    uint u = __float_as_uint(f);
    return (ushort)((u + 0x7FFFu + ((u >> 16) & 1u)) >> 16);
}
__device__ inline float bf2f(ushort h) { return __uint_as_float(((uint)h) << 16); }
__device__ inline uint pk2(ushort a, ushort b) { return (uint)a | ((uint)b << 16); }

// Direct HBM->LDS DMA, 16B per lane. LDS dest = wave-uniform base + lane*16.
__device__ __forceinline__ void load_lds16(const ushort* g, ushort* l) {
    __builtin_amdgcn_global_load_lds(
        (const __attribute__((address_space(1))) void*)g,
        (__attribute__((address_space(3))) void*)l, 16, 0, 0);
}

// ---------------------------------------------------------------------------
// transp_conv: src fp32 [192][65536] -> hi/lo bf16 planes TRANSPOSED [65536][192].
// Tile 32c x 64n via LDS. Used for x only (v-path fused into dwconv_vt).
// ---------------------------------------------------------------------------
__global__ __launch_bounds__(256) void transp_conv(
    const float* __restrict__ src, ushort* __restrict__ hi, ushort* __restrict__ lo)
{
    __shared__ float T[32][65];
    const int t = threadIdx.x;
    const int n0 = blockIdx.x * 64, c0 = blockIdx.y * 32;
    {
        const int cb = t >> 6, n = t & 63;
        #pragma unroll
        for (int i = 0; i < 8; ++i) {
            const int c = cb + i * 4;
            T[c][n] = src[(long long)(c0 + c) * N_SP + n0 + n];
        }
    }
    __syncthreads();
    const int n = t >> 2, cq = (t & 3) * 8;
    float v[8];
    #pragma unroll
    for (int j = 0; j < 8; ++j) v[j] = T[cq + j][n];
    ushort h[8], l[8];
    #pragma unroll
    for (int j = 0; j < 8; ++j) { h[j] = f2bf(v[j]); l[j] = f2bf(v[j] - bf2f(h[j])); }
    uint4 H, L;
    H.x = pk2(h[0], h[1]); H.y = pk2(h[2], h[3]); H.z = pk2(h[4], h[5]); H.w = pk2(h[6], h[7]);
    L.x = pk2(l[0], l[1]); L.y = pk2(l[2], l[3]); L.z = pk2(l[4], l[5]); L.w = pk2(l[6], l[7]);
    const long long o = (long long)(n0 + n) * 192 + c0 + cq;
    *(uint4*)(hi + o) = H;
    *(uint4*)(lo + o) = L;
}

// ---------------------------------------------------------------------------
// gemm_mfma: C[m][n] = sum_k Wf[wrow0+m][k] * X[k][n], K=192, split-bf16:
// C = Whi*Xhi + Whi*Xlo + Wlo*Xhi (lo*lo dropped, ~1e-5 rel).
// Round-14: T3/T4-minimum 2-phase pipeline (guide-verified recipe):
//  - LDS double-buffered (W [64][32] + X [256][32] linear, dbuf = 80KB exactly
//    -> 2 blocks/CU);
//  - per K-step: issue stage(ks+1) [2 W global_loads into NAMED float4 regs +
//    8 global_load_lds] BEFORE the MFMA section on buf[ks&1]; vmcnt(0) only
//    AFTER the MFMAs (stage flies under ~48 MFMA); convert+ds_write W;
//    lgkmcnt(0); RAW s_barrier (NOT __syncthreads -- its vmcnt(0)-drain
//    before s_barrier would kill the overlap).
//  - sched_barrier(0) pins stage-issue before MFMA and guards rule-18 hoist.
// Round-10 tripwire: no uint4 prefetch arrays, no launch_bounds min-waves
// (spilled to scratch: VGPR 80 + WRITE 389MB). Named wa/wb only.
// Round-9: LDS read bank conflicts (W now 8-way) are off the critical path.
// C/D (m89): col=lane&15, row=(lane>>4)*4+j.
// ---------------------------------------------------------------------------
__global__ __launch_bounds__(256) void gemm_mfma(
    const float* __restrict__ Wf, int wrow0,
    const ushort* __restrict__ XtHi, const ushort* __restrict__ XtLo,
    float* __restrict__ C)
{
    __shared__ ushort WsH[2][2048], WsL[2][2048];   // [64][32] linear per buf
    __shared__ ushort XsH[2][8192], XsL[2][8192];   // [256][32] linear per buf
    const int t  = threadIdx.x;
    const int wv = t >> 6, l = t & 63;
    const int lc = l & 15, lg = l >> 4;
    const int m0 = blockIdx.y * 64;
    const long long n0 = (long long)blockIdx.x * 256;

    f32x4 acc[4][4];
    #pragma unroll
    for (int i = 0; i < 4; ++i)
        #pragma unroll
        for (int j = 0; j < 4; ++j) acc[i][j] = (f32x4)(0.f);

    const int ar = t >> 2, ak = (t & 3) * 8;
    const int rX  = wv * 64 + (l >> 2);
    const int koX = (l & 3) * 8;
    const float*  wbase = Wf + (long long)(wrow0 + m0 + ar) * 192 + ak;
    const ushort* gHb = XtHi + (n0 + rX) * 192 + koX;
    const ushort* gLb = XtLo + (n0 + rX) * 192 + koX;

    float4 wa, wb;   // named next-step W regs (no arrays: round-10 spill lesson)

    // ---- prologue: stage K-step 0 into buffer 0, full drain (overlap n/a here)
    wa = *(const float4*)(wbase);
    wb = *(const float4*)(wbase + 4);
    {
        ushort* lH = &XsH[0][(wv * 64) * 32];
        ushort* lL = &XsL[0][(wv * 64) * 32];
        #pragma unroll
        for (int i = 0; i < 4; ++i) {
            load_lds16(gHb + i * (16 * 192), lH + i * (16 * 32));
            load_lds16(gLb + i * (16 * 192), lL + i * (16 * 32));
        }
    }
    asm volatile("s_waitcnt vmcnt(0)" ::: "memory");
    {
        const float v0=wa.x,v1=wa.y,v2=wa.z,v3=wa.w,v4=wb.x,v5=wb.y,v6=wb.z,v7=wb.w;
        ushort h0=f2bf(v0),h1=f2bf(v1),h2=f2bf(v2),h3=f2bf(v3),
               h4=f2bf(v4),h5=f2bf(v5),h6=f2bf(v6),h7=f2bf(v7);
        uint4 H, L;
        H.x=pk2(h0,h1); H.y=pk2(h2,h3); H.z=pk2(h4,h5); H.w=pk2(h6,h7);
        L.x=pk2(f2bf(v0-bf2f(h0)),f2bf(v1-bf2f(h1)));
        L.y=pk2(f2bf(v2-bf2f(h2)),f2bf(v3-bf2f(h3)));
        L.z=pk2(f2bf(v4-bf2f(h4)),f2bf(v5-bf2f(h5)));
        L.w=pk2(f2bf(v6-bf2f(h6)),f2bf(v7-bf2f(h7)));
        *(uint4*)&WsH[0][ar * 32 + ak] = H;
        *(uint4*)&WsL[0][ar * 32 + ak] = L;
    }
    __syncthreads();

    #pragma unroll
    for (int ks = 0; ks < 6; ++ks) {
        const int cur = ks & 1, nxt = cur ^ 1;
        if (ks < 5) {
            // issue stage(ks+1): W-fp32 -> named regs, X -> LDS DMA (in flight
            // across the MFMA section below)
            const int kc = (ks + 1) * 32;
            wa = *(const float4*)(wbase + kc);
            wb = *(const float4*)(wbase + kc + 4);
            ushort* lH = &XsH[nxt][(wv * 64) * 32];
            ushort* lL = &XsL[nxt][(wv * 64) * 32];
            #pragma unroll
            for (int i = 0; i < 4; ++i) {
                load_lds16(gHb + kc + i * (16 * 192), lH + i * (16 * 32));
                load_lds16(gLb + kc + i * (16 * 192), lL + i * (16 * 32));
            }
            __builtin_amdgcn_sched_barrier(0);
        }
        // MFMA section on buffer `cur`
        {
            s16x8 ah[4], al[4];
            #pragma unroll
            for (int mf = 0; mf < 4; ++mf) {
                ah[mf] = *(const s16x8*)&WsH[cur][(mf * 16 + lc) * 32 + lg * 8];
                al[mf] = *(const s16x8*)&WsL[cur][(mf * 16 + lc) * 32 + lg * 8];
            }
            #pragma unroll
            for (int nf = 0; nf < 4; ++nf) {
                const int nr = wv * 64 + nf * 16 + lc;
                const s16x8 bh = *(const s16x8*)&XsH[cur][nr * 32 + lg * 8];
                const s16x8 bl = *(const s16x8*)&XsL[cur][nr * 32 + lg * 8];
                #pragma unroll
                for (int mf = 0; mf < 4; ++mf) {
                    acc[mf][nf] = __builtin_amdgcn_mfma_f32_16x16x32_bf16(ah[mf], bh, acc[mf][nf], 0, 0, 0);
                    acc[mf][nf] = __builtin_amdgcn_mfma_f32_16x16x32_bf16(ah[mf], bl, acc[mf][nf], 0, 0, 0);
                    acc[mf][nf] = __builtin_amdgcn_mfma_f32_16x16x32_bf16(al[mf], bh, acc[mf][nf], 0, 0, 0);
                }
            }
        }
        if (ks < 5) {
            asm volatile("s_waitcnt vmcnt(0)" ::: "memory");   // stage ks+1 landed
            {
                const float v0=wa.x,v1=wa.y,v2=wa.z,v3=wa.w,v4=wb.x,v5=wb.y,v6=wb.z,v7=wb.w;
                ushort h0=f2bf(v0),h1=f2bf(v1),h2=f2bf(v2),h3=f2bf(v3),
                       h4=f2bf(v4),h5=f2bf(v5),h6=f2bf(v6),h7=f2bf(v7);
                uint4 H, L;
                H.x=pk2(h0,h1); H.y=pk2(h2,h3); H.z=pk2(h4,h5); H.w=pk2(h6,h7);
                L.x=pk2(f2bf(v0-bf2f(h0)),f2bf(v1-bf2f(h1)));
                L.y=pk2(f2bf(v2-bf2f(h2)),f2bf(v3-bf2f(h3)));
                L.z=pk2(f2bf(v4-bf2f(h4)),f2bf(v5-bf2f(h5)));
                L.w=pk2(f2bf(v6-bf2f(h6)),f2bf(v7-bf2f(h7)));
                *(uint4*)&WsH[nxt][ar * 32 + ak] = H;
                *(uint4*)&WsL[nxt][ar * 32 + ak] = L;
            }
            asm volatile("s_waitcnt lgkmcnt(0)" ::: "memory"); // W writes visible
            __builtin_amdgcn_sched_barrier(0);
            __builtin_amdgcn_s_barrier();                      // RAW barrier
        }
    }

    #pragma unroll
    for (int mf = 0; mf < 4; ++mf)
        #pragma unroll
        for (int nf = 0; nf < 4; ++nf) {
            const long long nn = n0 + wv * 64 + nf * 16 + lc;
            #pragma unroll
            for (int j = 0; j < 4; ++j)
                C[(long long)(m0 + mf * 16 + lg * 4 + j) * N_SP + nn] = acc[mf][nf][j];
        }
}

// ---------------------------------------------------------------------------
// dwconv8: depthwise 3x3, register-shift, 8 px x 4 channels per thread (q,k
// paths; fp32 [c][n] output for gred). Halo via clamped loads + zeroed weights.
// ---------------------------------------------------------------------------
__global__ __launch_bounds__(256) void dwconv8(
    const float* __restrict__ src, const float* __restrict__ dww, float* __restrict__ dst)
{
    const int t = threadIdx.x;
    const int s = blockIdx.x * 256 + t;
    const int y = s >> 5;
    const int x8 = (s & 31) * 8;
    const int cg = blockIdx.y;

    const int xl = (x8 == 0) ? 0 : x8 - 4;
    const int xr = (x8 == 248) ? 248 : x8 + 8;

    #pragma unroll
    for (int i = 0; i < 4; ++i) {
        const int c = cg * 4 + i;
        const float* base = src + ((long long)c << 16);
        const float* wp = dww + c * 9;
        float acc[8];
        #pragma unroll
        for (int j = 0; j < 8; ++j) acc[j] = 0.f;
        #pragma unroll
        for (int dy = 0; dy < 3; ++dy) {
            const int yy = y + dy - 1;
            const bool vld = (yy >= 0 && yy < IMG);
            const float* row = base + (vld ? yy : y) * IMG;
            const float w0 = vld ? wp[dy * 3 + 0] : 0.f;
            const float w1 = vld ? wp[dy * 3 + 1] : 0.f;
            const float w2 = vld ? wp[dy * 3 + 2] : 0.f;
            const float4 Lq = *(const float4*)(row + xl);
            const float4 M0 = *(const float4*)(row + x8);
            const float4 M1 = *(const float4*)(row + x8 + 4);
            const float4 Rq = *(const float4*)(row + xr);
            float vv[10];
            vv[0] = (x8 == 0) ? 0.f : Lq.w;
            vv[1] = M0.x; vv[2] = M0.y; vv[3] = M0.z; vv[4] = M0.w;
            vv[5] = M1.x; vv[6] = M1.y; vv[7] = M1.z; vv[8] = M1.w;
            vv[9] = (x8 == 248) ? 0.f : Rq.x;
            #pragma unroll
            for (int j = 0; j < 8; ++j)
                acc[j] = fmaf(w0, vv[j], fmaf(w1, vv[j + 1], fmaf(w2, vv[j + 2], acc[j])));
        }
        float4 o0, o1;
        o0.x = acc[0]; o0.y = acc[1]; o0.z = acc[2]; o0.w = acc[3];
        o1.x = acc[4]; o1.y = acc[5]; o1.z = acc[6]; o1.w = acc[7];
        float* drow = dst + ((long long)c << 16) + y * IMG + x8;
        *(float4*)drow = o0;
        *(float4*)(drow + 4) = o1;
    }
}

// ---------------------------------------------------------------------------
// dwconv_vt: depthwise 3x3 on v + FUSED transpose-convert epilogue: writes
// hi/lo bf16 planes in [n][192] layout directly (K4's B format).
// Grid: (256 rows, 6 ch-groups).
// ---------------------------------------------------------------------------
__global__ __launch_bounds__(256) void dwconv_vt(
    const float* __restrict__ src, const float* __restrict__ dww,
    ushort* __restrict__ hi, ushort* __restrict__ lo)
{
    const int t = threadIdx.x;
    const int y  = blockIdx.x;
    const int cg = blockIdx.y;
    const int pxg = t & 31, chq = t >> 5;
    const int x8 = pxg * 8;
    const int c0 = cg * 32 + chq * 4;

    const int xl = (x8 == 0) ? 0 : x8 - 4;
    const int xr = (x8 == 248) ? 248 : x8 + 8;

    float accA[4][8];
    #pragma unroll
    for (int i = 0; i < 4; ++i) {
        const int c = c0 + i;
        const float* base = src + ((long long)c << 16);
        const float* wp = dww + c * 9;
        #pragma unroll
        for (int j = 0; j < 8; ++j) accA[i][j] = 0.f;
        #pragma unroll
        for (int dy = 0; dy < 3; ++dy) {
            const int yy = y + dy - 1;
            const bool vld = (yy >= 0 && yy < IMG);
            const float* row = base + (vld ? yy : y) * IMG;
            const float w0 = vld ? wp[dy * 3 + 0] : 0.f;
            const float w1 = vld ? wp[dy * 3 + 1] : 0.f;
            const float w2 = vld ? wp[dy * 3 + 2] : 0.f;
            const float4 Lq = *(const float4*)(row + xl);
            const float4 M0 = *(const float4*)(row + x8);
            const float4 M1 = *(const float4*)(row + x8 + 4);
            const float4 Rq = *(const float4*)(row + xr);
            float vv[10];
            vv[0] = (x8 == 0) ? 0.f : Lq.w;
            vv[1] = M0.x; vv[2] = M0.y; vv[3] = M0.z; vv[4] = M0.w;
            vv[5] = M1.x; vv[6] = M1.y; vv[7] = M1.z; vv[8] = M1.w;
            vv[9] = (x8 == 248) ? 0.f : Rq.x;
            #pragma unroll
            for (int j = 0; j < 8; ++j)
                accA[i][j] = fmaf(w0, vv[j], fmaf(w1, vv[j + 1], fmaf(w2, vv[j + 2], accA[i][j])));
        }
    }
    const long long nbase = (long long)y * 256 + x8;
    #pragma unroll
    for (int j = 0; j < 8; ++j) {
        ushort h4[4], l4[4];
        #pragma unroll
        for (int i = 0; i < 4; ++i) {
            const float v = accA[i][j];
            h4[i] = f2bf(v);
            l4[i] = f2bf(v - bf2f(h4[i]));
        }
        uint2 H, L;
        H.x = pk2(h4[0], h4[1]); H.y = pk2(h4[2], h4[3]);
        L.x = pk2(l4[0], l4[1]); L.y = pk2(l4[2], l4[3]);
        const long long o = (nbase + j) * 192 + c0;
        *(uint2*)(hi + o) = H;
        *(uint2*)(lo + o) = L;
    }
}

// ---------------------------------------------------------------------------
// gred: G/Sq/Sk partials from post-DW q,k. Round-13: q,k tiles staged in LDS
// once (coalesced, unique); compute reads LDS (8-lane sharing = broadcast).
// Reduction scratch overlays staging LDS. No atomics.
// ---------------------------------------------------------------------------
__global__ __launch_bounds__(256) void gred(
    const float* __restrict__ q, const float* __restrict__ k, float* __restrict__ Gpart)
{
    __shared__ float smem[8448];          // qs: [0,4224) ks: [4224,8448); stride 132
    float* qs = smem;
    float* ks = smem + 4224;
    const int t = threadIdx.x;
    const int blk = blockIdx.x, h = blockIdx.y;
    const int w = t >> 6, l = t & 63;
    const int cqd = l >> 3, dqd = l & 7;

    float acc[4][4];
    #pragma unroll
    for (int i = 0; i < 4; ++i) { acc[i][0]=0.f; acc[i][1]=0.f; acc[i][2]=0.f; acc[i][3]=0.f; }
    float sq[4] = {0.f,0.f,0.f,0.f}, sk[4] = {0.f,0.f,0.f,0.f};

    const float* qh = q + ((long long)(h * 32) << 16);
    const float* kh = k + ((long long)(h * 32) << 16);

    for (int s = 0; s < 4; ++s) {
        const int n0s = blk * 512 + s * 128;
        #pragma unroll
        for (int i = 0; i < 4; ++i) {
            const int f4 = t + i * 256;
            const int ch = f4 >> 5, n4 = (f4 & 31) * 4;
            const long long go = ((long long)ch << 16) + n0s + n4;
            *(float4*)&qs[ch * 132 + n4] = *(const float4*)(qh + go);
            *(float4*)&ks[ch * 132 + n4] = *(const float4*)(kh + go);
        }
        __syncthreads();
        const int nb = w * 32;
        #pragma unroll
        for (int it = 0; it < 8; ++it) {
            const int n = nb + it * 4;
            float4 qa[4], kb[4];
            #pragma unroll
            for (int i = 0; i < 4; ++i) qa[i] = *(const float4*)&qs[(cqd * 4 + i) * 132 + n];
            #pragma unroll
            for (int j = 0; j < 4; ++j) kb[j] = *(const float4*)&ks[(dqd * 4 + j) * 132 + n];
            #pragma unroll
            for (int i = 0; i < 4; ++i) {
                #pragma unroll
                for (int j = 0; j < 4; ++j) {
                    acc[i][j] = fmaf(qa[i].x, kb[j].x, acc[i][j]);
                    acc[i][j] = fmaf(qa[i].y, kb[j].y, acc[i][j]);
                    acc[i][j] = fmaf(qa[i].z, kb[j].z, acc[i][j]);
                    acc[i][j] = fmaf(qa[i].w, kb[j].w, acc[i][j]);
                }
            }
            if (dqd == 0) {
                #pragma unroll
                for (int i = 0; i < 4; ++i) {
                    sq[i] = fmaf(qa[i].x, qa[i].x, sq[i]);
                    sq[i] = fmaf(qa[i].y, qa[i].y, sq[i]);
                    sq[i] = fmaf(qa[i].z, qa[i].z, sq[i]);
                    sq[i] = fmaf(qa[i].w, qa[i].w, sq[i]);
                }
            }
            if (cqd == 0) {
                #pragma unroll
                for (int j = 0; j < 4; ++j) {
                    sk[j] = fmaf(kb[j].x, kb[j].x, sk[j]);
                    sk[j] = fmaf(kb[j].y, kb[j].y, sk[j]);
                    sk[j] = fmaf(kb[j].z, kb[j].z, sk[j]);
                    sk[j] = fmaf(kb[j].w, kb[j].w, sk[j]);
                }
            }
        }
        __syncthreads();
    }

    float* red  = smem;                   // overlays (staging dead post-barrier)
    float* red2 = smem + 4096;
    #pragma unroll
    for (int i = 0; i < 4; ++i) {
        #pragma unroll
        for (int j = 0; j < 4; ++j)
            red[w * 1024 + (cqd * 4 + i) * 32 + dqd * 4 + j] = acc[i][j];
    }
    if (dqd == 0) {
        #pragma unroll
        for (int i = 0; i < 4; ++i) red2[w * 32 + cqd * 4 + i] = sq[i];
    }
    if (cqd == 0) {
        #pragma unroll
        for (int j = 0; j < 4; ++j) red2[128 + w * 32 + dqd * 4 + j] = sk[j];
    }
    __syncthreads();

    float* Gp = Gpart + (long long)(h * 128 + blk) * 1088;
    #pragma unroll
    for (int i = 0; i < 4; ++i) {
        int slot = t + i * 256;
        Gp[slot] = red[slot] + red[1024 + slot] + red[2048 + slot] + red[3072 + slot];
    }
    if (t < 32) {
        Gp[1024 + t] = red2[t] + red2[32 + t] + red2[64 + t] + red2[96 + t];
    } else if (t < 64) {
        int c = t - 32;
        Gp[1056 + c] = red2[128 + c] + red2[160 + c] + red2[192 + c] + red2[224 + c];
    }
}

__global__ void reduce_g(const float* __restrict__ Gpart, float* __restrict__ G,
                         float* __restrict__ Sq, float* __restrict__ Sk, int bh0)
{
    const int h = blockIdx.x, t = threadIdx.x;
    const float* Gp = Gpart + (long long)h * 128 * 1088;
    const int bh = bh0 + h;
    #pragma unroll
    for (int i = 0; i < 5; ++i) {
        int slot = t + i * 256;
        if (slot >= 1088) break;
        float s = 0.f;
        for (int tl = 0; tl < 128; ++tl) s += Gp[(long long)tl * 1088 + slot];
        if (slot < 1024)      G[(long long)bh * 1024 + slot] = s;
        else if (slot < 1056) Sq[bh * 32 + (slot - 1024)] = s;
        else                  Sk[bh * 32 + (slot - 1056)] = s;
    }
}

__global__ void attn_small(const float* __restrict__ G, const float* __restrict__ Sq,
                           const float* __restrict__ Sk, const float* __restrict__ temp,
                           const float* __restrict__ attn1, float* __restrict__ A)
{
    const int h = blockIdx.x, b = blockIdx.y, c = threadIdx.x;
    const int bh = b * 6 + h;
    const float* g = G + ((long long)bh * 32 + c) * 32;
    const float nq = fmaxf(sqrtf(Sq[bh * 32 + c]), 1e-12f);
    const float T  = temp[h];
    const float a1 = attn1[0];

    float a[32];
    #pragma unroll
    for (int d = 0; d < 32; ++d) {
        float nk = fmaxf(sqrtf(Sk[bh * 32 + d]), 1e-12f);
        a[d] = g[d] / (nq * nk) * T;
    }
    unsigned mask = 0u;
    float m = 0.f, kth = 0.f;
    for (int it = 0; it < 16; ++it) {
        float best = -3.4e38f; int bi = 0;
        #pragma unroll
        for (int d = 0; d < 32; ++d) {
            bool avail = ((mask >> d) & 1u) == 0u;
            if (avail && a[d] > best) { best = a[d]; bi = d; }
        }
        mask |= (1u << bi);
        if (it == 0) m = best;
        kth = best;
    }
    float denom = 0.f;
    #pragma unroll
    for (int d = 0; d < 32; ++d) if (a[d] >= kth) denom += expf(a[d] - m);
    const float inv = a1 / denom;
    float* Ar = A + ((long long)bh * 32 + c) * 32;
    #pragma unroll
    for (int d = 0; d < 32; ++d) Ar[d] = (a[d] >= kth) ? expf(a[d] - m) * inv : 0.f;
}

__global__ void make_m(const float* __restrict__ proj_w, const float* __restrict__ A,
                       float* __restrict__ M)
{
    const int o = blockIdx.x, b = blockIdx.y, j = threadIdx.x;
    const int hd = j >> 5, d = j & 31;
    const float* pw = proj_w + o * 192 + hd * 32;
    const float* Ah = A + ((long long)(b * 6 + hd) * 32) * 32 + d;
    float s = 0.f;
    #pragma unroll
    for (int cq = 0; cq < 32; ++cq) s = fmaf(pw[cq], Ah[cq * 32], s);
    M[((long long)(b * 192 + o)) * 192 + j] = s;
}

// ---------------------------------------------------------------------------
extern "C" void kernel_launch(void* const* d_in, const int* in_sizes, int n_in,
                              void* d_out, int out_size, void* d_ws, size_t ws_size,
                              hipStream_t stream)
{
    const float* x      = (const float*)d_in[0];
    const float* qkv_w  = (const float*)d_in[1];
    const float* dww    = (const float*)d_in[2];
    const float* proj_w = (const float*)d_in[3];
    const float* temp   = (const float*)d_in[4];
    const float* attn1  = (const float*)d_in[5];
    float* out = (float*)d_out;
    float* wsf = (float*)d_ws;

    // ws layout (floats) -- total = proven-safe 101,059,584 bytes
    float* G   = wsf;                 // 12,288
    float* Sq  = G + 12288;           // 384
    float* Sk  = Sq + 384;            // 384
    float* A   = Sk + 384;            // 12,288
    float* Mm  = A + 12288;           // 73,728
    float* buf = Mm + 73728;          // 96 MiB

    const long long PL = 12582912LL;  // floats per 48 MiB region
    float* W1 = buf;
    float* W2 = buf + PL;
    float* R1 = out;                  // batch-0 out region
    float* R2 = out + PL;             // batch-1 out region

    ushort* R1H = (ushort*)R1; ushort* R1L = R1H + PL;
    ushort* W1H = (ushort*)W1; ushort* W1L = W1H + PL;

    // ---- Phase S, b=0
    transp_conv<<<dim3(1024, 6), 256, 0, stream>>>(x, R1H, R1L);
    gemm_mfma<<<dim3(256, 6), 256, 0, stream>>>(qkv_w, 0, R1H, R1L, buf);
    dwconv8<<<dim3(32, 48), 256, 0, stream>>>(W1, dww, R2);            // qpost
    dwconv8<<<dim3(32, 48), 256, 0, stream>>>(W2, dww + 192 * 9, W1);  // kpost
    gred<<<dim3(128, 6), 256, 0, stream>>>(R2, W1, W2);
    reduce_g<<<dim3(6, 1), 256, 0, stream>>>(W2, G, Sq, Sk, 0);

    // ---- Phase S, b=1: Xt(x1)@R1 stays ALIVE for the v-path
    transp_conv<<<dim3(1024, 6), 256, 0, stream>>>(x + PL, R1H, R1L);
    gemm_mfma<<<dim3(256, 6), 256, 0, stream>>>(qkv_w, 0, R1H, R1L, buf);
    dwconv8<<<dim3(32, 48), 256, 0, stream>>>(W1, dww, R2);
    dwconv8<<<dim3(32, 48), 256, 0, stream>>>(W2, dww + 192 * 9, W1);
    gred<<<dim3(128, 6), 256, 0, stream>>>(R2, W1, W2);
    reduce_g<<<dim3(6, 1), 256, 0, stream>>>(W2, G, Sq, Sk, 6);

    // ---- Phase B: tiny attention matrices + fused projection matrices
    attn_small<<<dim3(6, 2), 32, 0, stream>>>(G, Sq, Sk, temp, attn1, A);
    make_m<<<dim3(192, 2), 192, 0, stream>>>(proj_w, A, Mm);

    // ---- V+K4, b=1 (reuses Xt(x1)@R1): K1v->W2 ; dwconv_vt: W2 -> W1 planes ; K4->R2
    gemm_mfma<<<dim3(256, 3), 256, 0, stream>>>(qkv_w, 384, R1H, R1L, W2);
    dwconv_vt<<<dim3(256, 6), 256, 0, stream>>>(W2, dww + 384 * 9, W1H, W1L);
    gemm_mfma<<<dim3(256, 3), 256, 0, stream>>>(Mm + 36864, 0, W1H, W1L, R2);

    // ---- V+K4, b=0: Xt(x0)@R1 ; K1v->W2 ; dwconv_vt: W2 -> W1 planes ; K4->R1 (final)
    transp_conv<<<dim3(1024, 6), 256, 0, stream>>>(x, R1H, R1L);
    gemm_mfma<<<dim3(256, 3), 256, 0, stream>>>(qkv_w, 384, R1H, R1L, W2);
    dwconv_vt<<<dim3(256, 6), 256, 0, stream>>>(W2, dww + 384 * 9, W1H, W1L);
    gemm_mfma<<<dim3(256, 3), 256, 0, stream>>>(Mm, 0, W1H, W1L, R1);
}

// Round 15
// 690.353 us; speedup vs baseline: 1.0248x; 1.0248x over previous
//
#include <hip/hip_runtime.h>
#include <math.h>

#define N_SP 65536   // h*w
#define IMG  256

typedef __attribute__((ext_vector_type(8))) short s16x8;
typedef __attribute__((ext_vector_type(4))) float f32x4;

// RNE fp32->bf16 (bit version, deterministic) and back
__device__ inline ushort f2bf(float f) {
    uint u = __float_as_uint(f);
    return (ushort)((u + 0x7FFFu + ((u >> 16) & 1u)) >> 16);
}
__device__ inline float bf2f(ushort h) { return __uint_as_float(((uint)h) << 16); }
__device__ inline uint pk2(ushort a, ushort b) { return (uint)a | ((uint)b << 16); }

// Direct HBM->LDS DMA, 16B per lane. LDS dest = wave-uniform base + lane*16.
__device__ __forceinline__ void load_lds16(const ushort* g, ushort* l) {
    __builtin_amdgcn_global_load_lds(
        (const __attribute__((address_space(1))) void*)g,
        (__attribute__((address_space(3))) void*)l, 16, 0, 0);
}

// ---------------------------------------------------------------------------
// conv_w: fp32 [rows][192] -> hi/lo bf16 planes [rows][192] (row-major, k
// contiguous -- the MFMA A-operand layout). One-time tiny kernel; removes the
// ~90-VALU-op/thread/K-step W conversion from gemm (round-15: that redundant
// conversion ran in all 256 n-blocks and rivaled the MFMA section itself).
// grid: rows*24/256 blocks.
// ---------------------------------------------------------------------------
__global__ __launch_bounds__(256) void conv_w(
    const float* __restrict__ src, ushort* __restrict__ hi, ushort* __restrict__ lo)
{
    const int id8 = blockIdx.x * 256 + threadIdx.x;   // 8-elem chunk index
    const long long o = (long long)id8 * 8;
    const float4 a0 = *(const float4*)(src + o);
    const float4 a1 = *(const float4*)(src + o + 4);
    const float v[8] = {a0.x, a0.y, a0.z, a0.w, a1.x, a1.y, a1.z, a1.w};
    ushort h[8], l[8];
    #pragma unroll
    for (int j = 0; j < 8; ++j) { h[j] = f2bf(v[j]); l[j] = f2bf(v[j] - bf2f(h[j])); }
    uint4 H, L;
    H.x = pk2(h[0], h[1]); H.y = pk2(h[2], h[3]); H.z = pk2(h[4], h[5]); H.w = pk2(h[6], h[7]);
    L.x = pk2(l[0], l[1]); L.y = pk2(l[2], l[3]); L.z = pk2(l[4], l[5]); L.w = pk2(l[6], l[7]);
    *(uint4*)(hi + o) = H;
    *(uint4*)(lo + o) = L;
}

// ---------------------------------------------------------------------------
// transp_conv: src fp32 [192][65536] -> hi/lo bf16 planes TRANSPOSED [65536][192].
// Tile 32c x 64n via LDS. Used for x only (v-path fused into dwconv_vt).
// ---------------------------------------------------------------------------
__global__ __launch_bounds__(256) void transp_conv(
    const float* __restrict__ src, ushort* __restrict__ hi, ushort* __restrict__ lo)
{
    __shared__ float T[32][65];
    const int t = threadIdx.x;
    const int n0 = blockIdx.x * 64, c0 = blockIdx.y * 32;
    {
        const int cb = t >> 6, n = t & 63;
        #pragma unroll
        for (int i = 0; i < 8; ++i) {
            const int c = cb + i * 4;
            T[c][n] = src[(long long)(c0 + c) * N_SP + n0 + n];
        }
    }
    __syncthreads();
    const int n = t >> 2, cq = (t & 3) * 8;
    float v[8];
    #pragma unroll
    for (int j = 0; j < 8; ++j) v[j] = T[cq + j][n];
    ushort h[8], l[8];
    #pragma unroll
    for (int j = 0; j < 8; ++j) { h[j] = f2bf(v[j]); l[j] = f2bf(v[j] - bf2f(h[j])); }
    uint4 H, L;
    H.x = pk2(h[0], h[1]); H.y = pk2(h[2], h[3]); H.z = pk2(h[4], h[5]); H.w = pk2(h[6], h[7]);
    L.x = pk2(l[0], l[1]); L.y = pk2(l[2], l[3]); L.z = pk2(l[4], l[5]); L.w = pk2(l[6], l[7]);
    const long long o = (long long)(n0 + n) * 192 + c0 + cq;
    *(uint4*)(hi + o) = H;
    *(uint4*)(lo + o) = L;
}

// ---------------------------------------------------------------------------
// gemm_mfma_p: C[m][n] = sum_k W[wrow0+m][k] * X[k][n], K=192, split-bf16,
// with BOTH operands pre-converted planes -> the whole stage is 12x
// global_load_lds per thread, zero staging VALU in the K-loop.
// Round-13 proven structure (single buffer, 2x __syncthreads per K-step);
// round-14's 2-phase dbuf regressed (80KB LDS -> 2 blocks/CU, 66->81us);
// round-10: no prefetch reg arrays / min-wave bounds (scratch spill).
// C/D (m89): col=lane&15, row=(lane>>4)*4+j.
// ---------------------------------------------------------------------------
__global__ __launch_bounds__(256) void gemm_mfma_p(
    const ushort* __restrict__ WtH, const ushort* __restrict__ WtL, int wrow0,
    const ushort* __restrict__ XtHi, const ushort* __restrict__ XtLo,
    float* __restrict__ C)
{
    __shared__ ushort WsH[64 * 32], WsL[64 * 32];     // [64][32] linear
    __shared__ ushort XsH[256 * 32], XsL[256 * 32];   // [256][32] linear
    const int t  = threadIdx.x;
    const int wv = t >> 6, l = t & 63;
    const int lc = l & 15, lg = l >> 4;
    const int m0 = blockIdx.y * 64;
    const long long n0 = (long long)blockIdx.x * 256;

    f32x4 acc[4][4];
    #pragma unroll
    for (int i = 0; i < 4; ++i)
        #pragma unroll
        for (int j = 0; j < 4; ++j) acc[i][j] = (f32x4)(0.f);

    // X DMA geometry: wave wv stages rows [wv*64, wv*64+64), lane l -> row
    // wv*64+(l>>2), ko (l&3)*8; LDS lane-offset l*16B matches linear [r][ko].
    const int rX  = wv * 64 + (l >> 2);
    const int koX = (l & 3) * 8;
    ushort* lXH = &XsH[(wv * 64) * 32];
    ushort* lXL = &XsL[(wv * 64) * 32];
    const ushort* gXH = XtHi + (n0 + rX) * 192 + koX;
    const ushort* gXL = XtLo + (n0 + rX) * 192 + koX;
    // W DMA geometry: wave wv stages W rows [wv*16, wv*16+16) (1 instr/plane).
    const int rW  = wv * 16 + (l >> 2);
    const int koW = (l & 3) * 8;
    ushort* lWH = &WsH[(wv * 16) * 32];
    ushort* lWL = &WsL[(wv * 16) * 32];
    const ushort* gWH = WtH + (long long)(wrow0 + m0 + rW) * 192 + koW;
    const ushort* gWL = WtL + (long long)(wrow0 + m0 + rW) * 192 + koW;

    for (int kc = 0; kc < 192; kc += 32) {
        load_lds16(gWH + kc, lWH);
        load_lds16(gWL + kc, lWL);
        #pragma unroll
        for (int i = 0; i < 4; ++i) {
            load_lds16(gXH + kc + i * (16 * 192), lXH + i * (16 * 32));
            load_lds16(gXL + kc + i * (16 * 192), lXL + i * (16 * 32));
        }
        __syncthreads();

        s16x8 ah[4], al[4];
        #pragma unroll
        for (int mf = 0; mf < 4; ++mf) {
            ah[mf] = *(const s16x8*)&WsH[(mf * 16 + lc) * 32 + lg * 8];
            al[mf] = *(const s16x8*)&WsL[(mf * 16 + lc) * 32 + lg * 8];
        }
        #pragma unroll
        for (int nf = 0; nf < 4; ++nf) {
            const int nr = wv * 64 + nf * 16 + lc;
            const s16x8 bh = *(const s16x8*)&XsH[nr * 32 + lg * 8];
            const s16x8 bl = *(const s16x8*)&XsL[nr * 32 + lg * 8];
            #pragma unroll
            for (int mf = 0; mf < 4; ++mf) {
                acc[mf][nf] = __builtin_amdgcn_mfma_f32_16x16x32_bf16(ah[mf], bh, acc[mf][nf], 0, 0, 0);
                acc[mf][nf] = __builtin_amdgcn_mfma_f32_16x16x32_bf16(ah[mf], bl, acc[mf][nf], 0, 0, 0);
                acc[mf][nf] = __builtin_amdgcn_mfma_f32_16x16x32_bf16(al[mf], bh, acc[mf][nf], 0, 0, 0);
            }
        }
        __syncthreads();
    }

    #pragma unroll
    for (int mf = 0; mf < 4; ++mf)
        #pragma unroll
        for (int nf = 0; nf < 4; ++nf) {
            const long long nn = n0 + wv * 64 + nf * 16 + lc;
            #pragma unroll
            for (int j = 0; j < 4; ++j)
                C[(long long)(m0 + mf * 16 + lg * 4 + j) * N_SP + nn] = acc[mf][nf][j];
        }
}

// ---------------------------------------------------------------------------
// gemm_mfma: round-13 version (in-kernel W conversion) -- FALLBACK ONLY when
// ws_size lacks room for the W planes. Proven 66us.
// ---------------------------------------------------------------------------
__global__ __launch_bounds__(256) void gemm_mfma(
    const float* __restrict__ Wf, int wrow0,
    const ushort* __restrict__ XtHi, const ushort* __restrict__ XtLo,
    float* __restrict__ C)
{
    __shared__ ushort WsH[64][40], WsL[64][40];
    __shared__ ushort XsH[256 * 32], XsL[256 * 32];
    const int t  = threadIdx.x;
    const int wv = t >> 6, l = t & 63;
    const int lc = l & 15, lg = l >> 4;
    const int m0 = blockIdx.y * 64;
    const long long n0 = (long long)blockIdx.x * 256;

    f32x4 acc[4][4];
    #pragma unroll
    for (int i = 0; i < 4; ++i)
        #pragma unroll
        for (int j = 0; j < 4; ++j) acc[i][j] = (f32x4)(0.f);

    const int ar = t >> 2, ak = (t & 3) * 8;
    const int rX  = wv * 64 + (l >> 2);
    const int koX = (l & 3) * 8;
    ushort* lH = &XsH[(wv * 64) * 32];
    ushort* lL = &XsL[(wv * 64) * 32];

    for (int kc = 0; kc < 192; kc += 32) {
        {
            const ushort* gH = XtHi + (n0 + rX) * 192 + kc + koX;
            const ushort* gL = XtLo + (n0 + rX) * 192 + kc + koX;
            #pragma unroll
            for (int i = 0; i < 4; ++i) {
                load_lds16(gH + i * (16 * 192), lH + i * (16 * 32));
                load_lds16(gL + i * (16 * 192), lL + i * (16 * 32));
            }
        }
        {
            const float* wp = Wf + (long long)(wrow0 + m0 + ar) * 192 + kc + ak;
            const float4 a0 = *(const float4*)wp;
            const float4 a1 = *(const float4*)(wp + 4);
            const float v[8] = {a0.x, a0.y, a0.z, a0.w, a1.x, a1.y, a1.z, a1.w};
            ushort h[8], lo_[8];
            #pragma unroll
            for (int j = 0; j < 8; ++j) { h[j] = f2bf(v[j]); lo_[j] = f2bf(v[j] - bf2f(h[j])); }
            uint4 H, L;
            H.x = pk2(h[0],h[1]); H.y = pk2(h[2],h[3]); H.z = pk2(h[4],h[5]); H.w = pk2(h[6],h[7]);
            L.x = pk2(lo_[0],lo_[1]); L.y = pk2(lo_[2],lo_[3]); L.z = pk2(lo_[4],lo_[5]); L.w = pk2(lo_[6],lo_[7]);
            *(uint4*)&WsH[ar][ak] = H;
            *(uint4*)&WsL[ar][ak] = L;
        }
        __syncthreads();

        s16x8 ah[4], al[4];
        #pragma unroll
        for (int mf = 0; mf < 4; ++mf) {
            ah[mf] = *(const s16x8*)&WsH[mf * 16 + lc][lg * 8];
            al[mf] = *(const s16x8*)&WsL[mf * 16 + lc][lg * 8];
        }
        #pragma unroll
        for (int nf = 0; nf < 4; ++nf) {
            const int nr = wv * 64 + nf * 16 + lc;
            const s16x8 bh = *(const s16x8*)&XsH[nr * 32 + lg * 8];
            const s16x8 bl = *(const s16x8*)&XsL[nr * 32 + lg * 8];
            #pragma unroll
            for (int mf = 0; mf < 4; ++mf) {
                acc[mf][nf] = __builtin_amdgcn_mfma_f32_16x16x32_bf16(ah[mf], bh, acc[mf][nf], 0, 0, 0);
                acc[mf][nf] = __builtin_amdgcn_mfma_f32_16x16x32_bf16(ah[mf], bl, acc[mf][nf], 0, 0, 0);
                acc[mf][nf] = __builtin_amdgcn_mfma_f32_16x16x32_bf16(al[mf], bh, acc[mf][nf], 0, 0, 0);
            }
        }
        __syncthreads();
    }

    #pragma unroll
    for (int mf = 0; mf < 4; ++mf)
        #pragma unroll
        for (int nf = 0; nf < 4; ++nf) {
            const long long nn = n0 + wv * 64 + nf * 16 + lc;
            #pragma unroll
            for (int j = 0; j < 4; ++j)
                C[(long long)(m0 + mf * 16 + lg * 4 + j) * N_SP + nn] = acc[mf][nf][j];
        }
}

// ---------------------------------------------------------------------------
// dwconv8: depthwise 3x3, register-shift, 8 px x 4 channels per thread (q,k
// paths; fp32 [c][n] output for gred). Halo via clamped loads + zeroed weights.
// ---------------------------------------------------------------------------
__global__ __launch_bounds__(256) void dwconv8(
    const float* __restrict__ src, const float* __restrict__ dww, float* __restrict__ dst)
{
    const int t = threadIdx.x;
    const int s = blockIdx.x * 256 + t;
    const int y = s >> 5;
    const int x8 = (s & 31) * 8;
    const int cg = blockIdx.y;

    const int xl = (x8 == 0) ? 0 : x8 - 4;
    const int xr = (x8 == 248) ? 248 : x8 + 8;

    #pragma unroll
    for (int i = 0; i < 4; ++i) {
        const int c = cg * 4 + i;
        const float* base = src + ((long long)c << 16);
        const float* wp = dww + c * 9;
        float acc[8];
        #pragma unroll
        for (int j = 0; j < 8; ++j) acc[j] = 0.f;
        #pragma unroll
        for (int dy = 0; dy < 3; ++dy) {
            const int yy = y + dy - 1;
            const bool vld = (yy >= 0 && yy < IMG);
            const float* row = base + (vld ? yy : y) * IMG;
            const float w0 = vld ? wp[dy * 3 + 0] : 0.f;
            const float w1 = vld ? wp[dy * 3 + 1] : 0.f;
            const float w2 = vld ? wp[dy * 3 + 2] : 0.f;
            const float4 Lq = *(const float4*)(row + xl);
            const float4 M0 = *(const float4*)(row + x8);
            const float4 M1 = *(const float4*)(row + x8 + 4);
            const float4 Rq = *(const float4*)(row + xr);
            float vv[10];
            vv[0] = (x8 == 0) ? 0.f : Lq.w;
            vv[1] = M0.x; vv[2] = M0.y; vv[3] = M0.z; vv[4] = M0.w;
            vv[5] = M1.x; vv[6] = M1.y; vv[7] = M1.z; vv[8] = M1.w;
            vv[9] = (x8 == 248) ? 0.f : Rq.x;
            #pragma unroll
            for (int j = 0; j < 8; ++j)
                acc[j] = fmaf(w0, vv[j], fmaf(w1, vv[j + 1], fmaf(w2, vv[j + 2], acc[j])));
        }
        float4 o0, o1;
        o0.x = acc[0]; o0.y = acc[1]; o0.z = acc[2]; o0.w = acc[3];
        o1.x = acc[4]; o1.y = acc[5]; o1.z = acc[6]; o1.w = acc[7];
        float* drow = dst + ((long long)c << 16) + y * IMG + x8;
        *(float4*)drow = o0;
        *(float4*)(drow + 4) = o1;
    }
}

// ---------------------------------------------------------------------------
// dwconv_vt: depthwise 3x3 on v + FUSED transpose-convert epilogue: writes
// hi/lo bf16 planes in [n][192] layout directly (K4's B format).
// Grid: (256 rows, 6 ch-groups).
// ---------------------------------------------------------------------------
__global__ __launch_bounds__(256) void dwconv_vt(
    const float* __restrict__ src, const float* __restrict__ dww,
    ushort* __restrict__ hi, ushort* __restrict__ lo)
{
    const int t = threadIdx.x;
    const int y  = blockIdx.x;
    const int cg = blockIdx.y;
    const int pxg = t & 31, chq = t >> 5;
    const int x8 = pxg * 8;
    const int c0 = cg * 32 + chq * 4;

    const int xl = (x8 == 0) ? 0 : x8 - 4;
    const int xr = (x8 == 248) ? 248 : x8 + 8;

    float accA[4][8];
    #pragma unroll
    for (int i = 0; i < 4; ++i) {
        const int c = c0 + i;
        const float* base = src + ((long long)c << 16);
        const float* wp = dww + c * 9;
        #pragma unroll
        for (int j = 0; j < 8; ++j) accA[i][j] = 0.f;
        #pragma unroll
        for (int dy = 0; dy < 3; ++dy) {
            const int yy = y + dy - 1;
            const bool vld = (yy >= 0 && yy < IMG);
            const float* row = base + (vld ? yy : y) * IMG;
            const float w0 = vld ? wp[dy * 3 + 0] : 0.f;
            const float w1 = vld ? wp[dy * 3 + 1] : 0.f;
            const float w2 = vld ? wp[dy * 3 + 2] : 0.f;
            const float4 Lq = *(const float4*)(row + xl);
            const float4 M0 = *(const float4*)(row + x8);
            const float4 M1 = *(const float4*)(row + x8 + 4);
            const float4 Rq = *(const float4*)(row + xr);
            float vv[10];
            vv[0] = (x8 == 0) ? 0.f : Lq.w;
            vv[1] = M0.x; vv[2] = M0.y; vv[3] = M0.z; vv[4] = M0.w;
            vv[5] = M1.x; vv[6] = M1.y; vv[7] = M1.z; vv[8] = M1.w;
            vv[9] = (x8 == 248) ? 0.f : Rq.x;
            #pragma unroll
            for (int j = 0; j < 8; ++j)
                accA[i][j] = fmaf(w0, vv[j], fmaf(w1, vv[j + 1], fmaf(w2, vv[j + 2], accA[i][j])));
        }
    }
    const long long nbase = (long long)y * 256 + x8;
    #pragma unroll
    for (int j = 0; j < 8; ++j) {
        ushort h4[4], l4[4];
        #pragma unroll
        for (int i = 0; i < 4; ++i) {
            const float v = accA[i][j];
            h4[i] = f2bf(v);
            l4[i] = f2bf(v - bf2f(h4[i]));
        }
        uint2 H, L;
        H.x = pk2(h4[0], h4[1]); H.y = pk2(h4[2], h4[3]);
        L.x = pk2(l4[0], l4[1]); L.y = pk2(l4[2], l4[3]);
        const long long o = (nbase + j) * 192 + c0;
        *(uint2*)(hi + o) = H;
        *(uint2*)(lo + o) = L;
    }
}

// ---------------------------------------------------------------------------
// gred: G/Sq/Sk partials from post-DW q,k. q,k tiles staged in LDS once
// (coalesced, unique); compute reads LDS (8-lane sharing = broadcast).
// Reduction scratch overlays staging LDS. No atomics.
// ---------------------------------------------------------------------------
__global__ __launch_bounds__(256) void gred(
    const float* __restrict__ q, const float* __restrict__ k, float* __restrict__ Gpart)
{
    __shared__ float smem[8448];          // qs: [0,4224) ks: [4224,8448); stride 132
    float* qs = smem;
    float* ks = smem + 4224;
    const int t = threadIdx.x;
    const int blk = blockIdx.x, h = blockIdx.y;
    const int w = t >> 6, l = t & 63;
    const int cqd = l >> 3, dqd = l & 7;

    float acc[4][4];
    #pragma unroll
    for (int i = 0; i < 4; ++i) { acc[i][0]=0.f; acc[i][1]=0.f; acc[i][2]=0.f; acc[i][3]=0.f; }
    float sq[4] = {0.f,0.f,0.f,0.f}, sk[4] = {0.f,0.f,0.f,0.f};

    const float* qh = q + ((long long)(h * 32) << 16);
    const float* kh = k + ((long long)(h * 32) << 16);

    for (int s = 0; s < 4; ++s) {
        const int n0s = blk * 512 + s * 128;
        #pragma unroll
        for (int i = 0; i < 4; ++i) {
            const int f4 = t + i * 256;
            const int ch = f4 >> 5, n4 = (f4 & 31) * 4;
            const long long go = ((long long)ch << 16) + n0s + n4;
            *(float4*)&qs[ch * 132 + n4] = *(const float4*)(qh + go);
            *(float4*)&ks[ch * 132 + n4] = *(const float4*)(kh + go);
        }
        __syncthreads();
        const int nb = w * 32;
        #pragma unroll
        for (int it = 0; it < 8; ++it) {
            const int n = nb + it * 4;
            float4 qa[4], kb[4];
            #pragma unroll
            for (int i = 0; i < 4; ++i) qa[i] = *(const float4*)&qs[(cqd * 4 + i) * 132 + n];
            #pragma unroll
            for (int j = 0; j < 4; ++j) kb[j] = *(const float4*)&ks[(dqd * 4 + j) * 132 + n];
            #pragma unroll
            for (int i = 0; i < 4; ++i) {
                #pragma unroll
                for (int j = 0; j < 4; ++j) {
                    acc[i][j] = fmaf(qa[i].x, kb[j].x, acc[i][j]);
                    acc[i][j] = fmaf(qa[i].y, kb[j].y, acc[i][j]);
                    acc[i][j] = fmaf(qa[i].z, kb[j].z, acc[i][j]);
                    acc[i][j] = fmaf(qa[i].w, kb[j].w, acc[i][j]);
                }
            }
            if (dqd == 0) {
                #pragma unroll
                for (int i = 0; i < 4; ++i) {
                    sq[i] = fmaf(qa[i].x, qa[i].x, sq[i]);
                    sq[i] = fmaf(qa[i].y, qa[i].y, sq[i]);
                    sq[i] = fmaf(qa[i].z, qa[i].z, sq[i]);
                    sq[i] = fmaf(qa[i].w, qa[i].w, sq[i]);
                }
            }
            if (cqd == 0) {
                #pragma unroll
                for (int j = 0; j < 4; ++j) {
                    sk[j] = fmaf(kb[j].x, kb[j].x, sk[j]);
                    sk[j] = fmaf(kb[j].y, kb[j].y, sk[j]);
                    sk[j] = fmaf(kb[j].z, kb[j].z, sk[j]);
                    sk[j] = fmaf(kb[j].w, kb[j].w, sk[j]);
                }
            }
        }
        __syncthreads();
    }

    float* red  = smem;                   // overlays (staging dead post-barrier)
    float* red2 = smem + 4096;
    #pragma unroll
    for (int i = 0; i < 4; ++i) {
        #pragma unroll
        for (int j = 0; j < 4; ++j)
            red[w * 1024 + (cqd * 4 + i) * 32 + dqd * 4 + j] = acc[i][j];
    }
    if (dqd == 0) {
        #pragma unroll
        for (int i = 0; i < 4; ++i) red2[w * 32 + cqd * 4 + i] = sq[i];
    }
    if (cqd == 0) {
        #pragma unroll
        for (int j = 0; j < 4; ++j) red2[128 + w * 32 + dqd * 4 + j] = sk[j];
    }
    __syncthreads();

    float* Gp = Gpart + (long long)(h * 128 + blk) * 1088;
    #pragma unroll
    for (int i = 0; i < 4; ++i) {
        int slot = t + i * 256;
        Gp[slot] = red[slot] + red[1024 + slot] + red[2048 + slot] + red[3072 + slot];
    }
    if (t < 32) {
        Gp[1024 + t] = red2[t] + red2[32 + t] + red2[64 + t] + red2[96 + t];
    } else if (t < 64) {
        int c = t - 32;
        Gp[1056 + c] = red2[128 + c] + red2[160 + c] + red2[192 + c] + red2[224 + c];
    }
}

__global__ void reduce_g(const float* __restrict__ Gpart, float* __restrict__ G,
                         float* __restrict__ Sq, float* __restrict__ Sk, int bh0)
{
    const int h = blockIdx.x, t = threadIdx.x;
    const float* Gp = Gpart + (long long)h * 128 * 1088;
    const int bh = bh0 + h;
    #pragma unroll
    for (int i = 0; i < 5; ++i) {
        int slot = t + i * 256;
        if (slot >= 1088) break;
        float s = 0.f;
        for (int tl = 0; tl < 128; ++tl) s += Gp[(long long)tl * 1088 + slot];
        if (slot < 1024)      G[(long long)bh * 1024 + slot] = s;
        else if (slot < 1056) Sq[bh * 32 + (slot - 1024)] = s;
        else                  Sk[bh * 32 + (slot - 1056)] = s;
    }
}

__global__ void attn_small(const float* __restrict__ G, const float* __restrict__ Sq,
                           const float* __restrict__ Sk, const float* __restrict__ temp,
                           const float* __restrict__ attn1, float* __restrict__ A)
{
    const int h = blockIdx.x, b = blockIdx.y, c = threadIdx.x;
    const int bh = b * 6 + h;
    const float* g = G + ((long long)bh * 32 + c) * 32;
    const float nq = fmaxf(sqrtf(Sq[bh * 32 + c]), 1e-12f);
    const float T  = temp[h];
    const float a1 = attn1[0];

    float a[32];
    #pragma unroll
    for (int d = 0; d < 32; ++d) {
        float nk = fmaxf(sqrtf(Sk[bh * 32 + d]), 1e-12f);
        a[d] = g[d] / (nq * nk) * T;
    }
    unsigned mask = 0u;
    float m = 0.f, kth = 0.f;
    for (int it = 0; it < 16; ++it) {
        float best = -3.4e38f; int bi = 0;
        #pragma unroll
        for (int d = 0; d < 32; ++d) {
            bool avail = ((mask >> d) & 1u) == 0u;
            if (avail && a[d] > best) { best = a[d]; bi = d; }
        }
        mask |= (1u << bi);
        if (it == 0) m = best;
        kth = best;
    }
    float denom = 0.f;
    #pragma unroll
    for (int d = 0; d < 32; ++d) if (a[d] >= kth) denom += expf(a[d] - m);
    const float inv = a1 / denom;
    float* Ar = A + ((long long)bh * 32 + c) * 32;
    #pragma unroll
    for (int d = 0; d < 32; ++d) Ar[d] = (a[d] >= kth) ? expf(a[d] - m) * inv : 0.f;
}

__global__ void make_m(const float* __restrict__ proj_w, const float* __restrict__ A,
                       float* __restrict__ M)
{
    const int o = blockIdx.x, b = blockIdx.y, j = threadIdx.x;
    const int hd = j >> 5, d = j & 31;
    const float* pw = proj_w + o * 192 + hd * 32;
    const float* Ah = A + ((long long)(b * 6 + hd) * 32) * 32 + d;
    float s = 0.f;
    #pragma unroll
    for (int cq = 0; cq < 32; ++cq) s = fmaf(pw[cq], Ah[cq * 32], s);
    M[((long long)(b * 192 + o)) * 192 + j] = s;
}

// ---------------------------------------------------------------------------
extern "C" void kernel_launch(void* const* d_in, const int* in_sizes, int n_in,
                              void* d_out, int out_size, void* d_ws, size_t ws_size,
                              hipStream_t stream)
{
    const float* x      = (const float*)d_in[0];
    const float* qkv_w  = (const float*)d_in[1];
    const float* dww    = (const float*)d_in[2];
    const float* proj_w = (const float*)d_in[3];
    const float* temp   = (const float*)d_in[4];
    const float* attn1  = (const float*)d_in[5];
    float* out = (float*)d_out;
    float* wsf = (float*)d_ws;

    // ws layout (floats): base = proven-safe 101,059,584 B; planes add 737,280 B
    float* G   = wsf;                 // 12,288
    float* Sq  = G + 12288;           // 384
    float* Sk  = Sq + 384;            // 384
    float* A   = Sk + 384;            // 12,288
    float* Mm  = A + 12288;           // 73,728 (fp32 M)
    ushort* WqH = (ushort*)(Mm + 73728);   // 110,592 u16 (qkv_w planes)
    ushort* WqL = WqH + 110592;            // 110,592
    ushort* MmH = WqL + 110592;            // 73,728 (M planes)
    ushort* MmL = MmH + 73728;             // 73,728
    float* bufP = (float*)(MmL + 73728);   // planes-path buf
    float* bufF = Mm + 73728;              // fallback buf (round-13 layout)

    const long long PL = 12582912LL;  // floats per 48 MiB region
    const bool planes = ws_size >= (size_t)101796864ULL;
    float* buf = planes ? bufP : bufF;
    float* W1 = buf;
    float* W2 = buf + PL;
    float* R1 = out;                  // batch-0 out region
    float* R2 = out + PL;             // batch-1 out region

    ushort* R1H = (ushort*)R1; ushort* R1L = R1H + PL;
    ushort* W1H = (ushort*)W1; ushort* W1L = W1H + PL;

    if (planes) {
        conv_w<<<dim3(54), 256, 0, stream>>>(qkv_w, WqH, WqL);   // 576*192/2048

        // ---- Phase S, b=0
        transp_conv<<<dim3(1024, 6), 256, 0, stream>>>(x, R1H, R1L);
        gemm_mfma_p<<<dim3(256, 6), 256, 0, stream>>>(WqH, WqL, 0, R1H, R1L, buf);
        dwconv8<<<dim3(32, 48), 256, 0, stream>>>(W1, dww, R2);
        dwconv8<<<dim3(32, 48), 256, 0, stream>>>(W2, dww + 192 * 9, W1);
        gred<<<dim3(128, 6), 256, 0, stream>>>(R2, W1, W2);
        reduce_g<<<dim3(6, 1), 256, 0, stream>>>(W2, G, Sq, Sk, 0);

        // ---- Phase S, b=1 (Xt(x1)@R1 stays alive for v-path)
        transp_conv<<<dim3(1024, 6), 256, 0, stream>>>(x + PL, R1H, R1L);
        gemm_mfma_p<<<dim3(256, 6), 256, 0, stream>>>(WqH, WqL, 0, R1H, R1L, buf);
        dwconv8<<<dim3(32, 48), 256, 0, stream>>>(W1, dww, R2);
        dwconv8<<<dim3(32, 48), 256, 0, stream>>>(W2, dww + 192 * 9, W1);
        gred<<<dim3(128, 6), 256, 0, stream>>>(R2, W1, W2);
        reduce_g<<<dim3(6, 1), 256, 0, stream>>>(W2, G, Sq, Sk, 6);

        // ---- Phase B
        attn_small<<<dim3(6, 2), 32, 0, stream>>>(G, Sq, Sk, temp, attn1, A);
        make_m<<<dim3(192, 2), 192, 0, stream>>>(proj_w, A, Mm);
        conv_w<<<dim3(36), 256, 0, stream>>>(Mm, MmH, MmL);      // 384*192/2048

        // ---- V+K4, b=1 (reuses Xt(x1)@R1)
        gemm_mfma_p<<<dim3(256, 3), 256, 0, stream>>>(WqH, WqL, 384, R1H, R1L, W2);
        dwconv_vt<<<dim3(256, 6), 256, 0, stream>>>(W2, dww + 384 * 9, W1H, W1L);
        gemm_mfma_p<<<dim3(256, 3), 256, 0, stream>>>(MmH, MmL, 192, W1H, W1L, R2);

        // ---- V+K4, b=0
        transp_conv<<<dim3(1024, 6), 256, 0, stream>>>(x, R1H, R1L);
        gemm_mfma_p<<<dim3(256, 3), 256, 0, stream>>>(WqH, WqL, 384, R1H, R1L, W2);
        dwconv_vt<<<dim3(256, 6), 256, 0, stream>>>(W2, dww + 384 * 9, W1H, W1L);
        gemm_mfma_p<<<dim3(256, 3), 256, 0, stream>>>(MmH, MmL, 0, W1H, W1L, R1);
    } else {
        // Fallback: round-13 exact path (in-kernel W conversion)
        transp_conv<<<dim3(1024, 6), 256, 0, stream>>>(x, R1H, R1L);
        gemm_mfma<<<dim3(256, 6), 256, 0, stream>>>(qkv_w, 0, R1H, R1L, buf);
        dwconv8<<<dim3(32, 48), 256, 0, stream>>>(W1, dww, R2);
        dwconv8<<<dim3(32, 48), 256, 0, stream>>>(W2, dww + 192 * 9, W1);
        gred<<<dim3(128, 6), 256, 0, stream>>>(R2, W1, W2);
        reduce_g<<<dim3(6, 1), 256, 0, stream>>>(W2, G, Sq, Sk, 0);

        transp_conv<<<dim3(1024, 6), 256, 0, stream>>>(x + PL, R1H, R1L);
        gemm_mfma<<<dim3(256, 6), 256, 0, stream>>>(qkv_w, 0, R1H, R1L, buf);
        dwconv8<<<dim3(32, 48), 256, 0, stream>>>(W1, dww, R2);
        dwconv8<<<dim3(32, 48), 256, 0, stream>>>(W2, dww + 192 * 9, W1);
        gred<<<dim3(128, 6), 256, 0, stream>>>(R2, W1, W2);
        reduce_g<<<dim3(6, 1), 256, 0, stream>>>(W2, G, Sq, Sk, 6);

        attn_small<<<dim3(6, 2), 32, 0, stream>>>(G, Sq, Sk, temp, attn1, A);
        make_m<<<dim3(192, 2), 192, 0, stream>>>(proj_w, A, Mm);

        gemm_mfma<<<dim3(256, 3), 256, 0, stream>>>(qkv_w, 384, R1H, R1L, W2);
        dwconv_vt<<<dim3(256, 6), 256, 0, stream>>>(W2, dww + 384 * 9, W1H, W1L);
        gemm_mfma<<<dim3(256, 3), 256, 0, stream>>>(Mm + 36864, 0, W1H, W1L, R2);

        transp_conv<<<dim3(1024, 6), 256, 0, stream>>>(x, R1H, R1L);
        gemm_mfma<<<dim3(256, 3), 256, 0, stream>>>(qkv_w, 384, R1H, R1L, W2);
        dwconv_vt<<<dim3(256, 6), 256, 0, stream>>>(W2, dww + 384 * 9, W1H, W1L);
        gemm_mfma<<<dim3(256, 3), 256, 0, stream>>>(Mm, 0, W1H, W1L, R1);
    }
}

// Round 16
// 601.253 us; speedup vs baseline: 1.1766x; 1.1482x over previous
//
#include <hip/hip_runtime.h>
#include <math.h>

#define N_SP 65536   // h*w
#define IMG  256

typedef __attribute__((ext_vector_type(8))) short s16x8;
typedef __attribute__((ext_vector_type(4))) float f32x4;

// RNE fp32->bf16 (bit version, deterministic) and back
__device__ inline ushort f2bf(float f) {
    uint u = __float_as_uint(f);
    return (ushort)((u + 0x7FFFu + ((u >> 16) & 1u)) >> 16);
}
__device__ inline float bf2f(ushort h) { return __uint_as_float(((uint)h) << 16); }
__device__ inline uint pk2(ushort a, ushort b) { return (uint)a | ((uint)b << 16); }

// Direct HBM->LDS DMA, 16B per lane. LDS dest = wave-uniform base + lane*16.
__device__ __forceinline__ void load_lds16(const ushort* g, ushort* l) {
    __builtin_amdgcn_global_load_lds(
        (const __attribute__((address_space(1))) void*)g,
        (__attribute__((address_space(3))) void*)l, 16, 0, 0);
}

// ---------------------------------------------------------------------------
// transp_conv: src fp32 [192][65536] -> hi/lo bf16 planes TRANSPOSED [65536][192].
// Tile 32c x 64n via LDS. Used for x only (v-path fused into dwconv_vt).
// ---------------------------------------------------------------------------
__global__ __launch_bounds__(256) void transp_conv(
    const float* __restrict__ src, ushort* __restrict__ hi, ushort* __restrict__ lo)
{
    __shared__ float T[32][65];
    const int t = threadIdx.x;
    const int n0 = blockIdx.x * 64, c0 = blockIdx.y * 32;
    {
        const int cb = t >> 6, n = t & 63;
        #pragma unroll
        for (int i = 0; i < 8; ++i) {
            const int c = cb + i * 4;
            T[c][n] = src[(long long)(c0 + c) * N_SP + n0 + n];
        }
    }
    __syncthreads();
    const int n = t >> 2, cq = (t & 3) * 8;
    float v[8];
    #pragma unroll
    for (int j = 0; j < 8; ++j) v[j] = T[cq + j][n];
    ushort h[8], l[8];
    #pragma unroll
    for (int j = 0; j < 8; ++j) { h[j] = f2bf(v[j]); l[j] = f2bf(v[j] - bf2f(h[j])); }
    uint4 H, L;
    H.x = pk2(h[0], h[1]); H.y = pk2(h[2], h[3]); H.z = pk2(h[4], h[5]); H.w = pk2(h[6], h[7]);
    L.x = pk2(l[0], l[1]); L.y = pk2(l[2], l[3]); L.z = pk2(l[4], l[5]); L.w = pk2(l[6], l[7]);
    const long long o = (long long)(n0 + n) * 192 + c0 + cq;
    *(uint4*)(hi + o) = H;
    *(uint4*)(lo + o) = L;
}

// ---------------------------------------------------------------------------
// gemm_mfma: C[m][n] = sum_k Wf[wrow0+m][k] * X[k][n], K=192, split-bf16:
// C = Whi*Xhi + Whi*Xlo + Wlo*Xhi (lo*lo dropped, ~1e-5 rel).
// ROUND-13 internals (proven 66us): X via global_load_lds, W converted
// in-kernel (round-15 proved conversion VALU is NOT on the critical path;
// round-14 dbuf and round-10 reg-prefetch both regressed -- do not revisit).
// ROUND-16: XCD-aware bijective block swizzle (guide T1). Flat grid nm*256;
// d = blockIdx.x: r=d&7, q=d>>3, j=q%nm (m-block), g=(q/nm)*8+r (n-block).
// Blocks d, d+8, ... share d%8 -> same XCD and same n-tile, temporally
// adjacent -> X planes fetched ~once per XCD instead of once per m-block.
// C/D (m89): col=lane&15, row=(lane>>4)*4+j.
// ---------------------------------------------------------------------------
__global__ __launch_bounds__(256) void gemm_mfma(
    const float* __restrict__ Wf, int wrow0, int nm,
    const ushort* __restrict__ XtHi, const ushort* __restrict__ XtLo,
    float* __restrict__ C)
{
    __shared__ ushort WsH[64][40], WsL[64][40];
    __shared__ ushort XsH[256 * 32], XsL[256 * 32];
    const int t  = threadIdx.x;
    const int wv = t >> 6, l = t & 63;
    const int lc = l & 15, lg = l >> 4;
    // bijective XCD swizzle: same-n m-blocks land on one XCD, adjacent in time
    const int d = blockIdx.x;
    const int r = d & 7, q = d >> 3;
    const int m0 = (q % nm) * 64;
    const long long n0 = (long long)((q / nm) * 8 + r) * 256;

    f32x4 acc[4][4];
    #pragma unroll
    for (int i = 0; i < 4; ++i)
        #pragma unroll
        for (int j = 0; j < 4; ++j) acc[i][j] = (f32x4)(0.f);

    const int ar = t >> 2, ak = (t & 3) * 8;
    const int rX  = wv * 64 + (l >> 2);
    const int koX = (l & 3) * 8;
    ushort* lH = &XsH[(wv * 64) * 32];
    ushort* lL = &XsL[(wv * 64) * 32];

    for (int kc = 0; kc < 192; kc += 32) {
        {
            const ushort* gH = XtHi + (n0 + rX) * 192 + kc + koX;
            const ushort* gL = XtLo + (n0 + rX) * 192 + kc + koX;
            #pragma unroll
            for (int i = 0; i < 4; ++i) {
                load_lds16(gH + i * (16 * 192), lH + i * (16 * 32));
                load_lds16(gL + i * (16 * 192), lL + i * (16 * 32));
            }
        }
        {
            const float* wp = Wf + (long long)(wrow0 + m0 + ar) * 192 + kc + ak;
            const float4 a0 = *(const float4*)wp;
            const float4 a1 = *(const float4*)(wp + 4);
            const float v[8] = {a0.x, a0.y, a0.z, a0.w, a1.x, a1.y, a1.z, a1.w};
            ushort h[8], lo_[8];
            #pragma unroll
            for (int j = 0; j < 8; ++j) { h[j] = f2bf(v[j]); lo_[j] = f2bf(v[j] - bf2f(h[j])); }
            uint4 H, L;
            H.x = pk2(h[0],h[1]); H.y = pk2(h[2],h[3]); H.z = pk2(h[4],h[5]); H.w = pk2(h[6],h[7]);
            L.x = pk2(lo_[0],lo_[1]); L.y = pk2(lo_[2],lo_[3]); L.z = pk2(lo_[4],lo_[5]); L.w = pk2(lo_[6],lo_[7]);
            *(uint4*)&WsH[ar][ak] = H;
            *(uint4*)&WsL[ar][ak] = L;
        }
        __syncthreads();

        s16x8 ah[4], al[4];
        #pragma unroll
        for (int mf = 0; mf < 4; ++mf) {
            ah[mf] = *(const s16x8*)&WsH[mf * 16 + lc][lg * 8];
            al[mf] = *(const s16x8*)&WsL[mf * 16 + lc][lg * 8];
        }
        #pragma unroll
        for (int nf = 0; nf < 4; ++nf) {
            const int nr = wv * 64 + nf * 16 + lc;
            const s16x8 bh = *(const s16x8*)&XsH[nr * 32 + lg * 8];
            const s16x8 bl = *(const s16x8*)&XsL[nr * 32 + lg * 8];
            #pragma unroll
            for (int mf = 0; mf < 4; ++mf) {
                acc[mf][nf] = __builtin_amdgcn_mfma_f32_16x16x32_bf16(ah[mf], bh, acc[mf][nf], 0, 0, 0);
                acc[mf][nf] = __builtin_amdgcn_mfma_f32_16x16x32_bf16(ah[mf], bl, acc[mf][nf], 0, 0, 0);
                acc[mf][nf] = __builtin_amdgcn_mfma_f32_16x16x32_bf16(al[mf], bh, acc[mf][nf], 0, 0, 0);
            }
        }
        __syncthreads();
    }

    #pragma unroll
    for (int mf = 0; mf < 4; ++mf)
        #pragma unroll
        for (int nf = 0; nf < 4; ++nf) {
            const long long nn = n0 + wv * 64 + nf * 16 + lc;
            #pragma unroll
            for (int j = 0; j < 4; ++j)
                C[(long long)(m0 + mf * 16 + lg * 4 + j) * N_SP + nn] = acc[mf][nf][j];
        }
}

// ---------------------------------------------------------------------------
// dwconv8: depthwise 3x3, register-shift, 8 px x 4 channels per thread (q,k
// paths; fp32 [c][n] output for gred). Halo via clamped loads + zeroed weights.
// ---------------------------------------------------------------------------
__global__ __launch_bounds__(256) void dwconv8(
    const float* __restrict__ src, const float* __restrict__ dww, float* __restrict__ dst)
{
    const int t = threadIdx.x;
    const int s = blockIdx.x * 256 + t;
    const int y = s >> 5;
    const int x8 = (s & 31) * 8;
    const int cg = blockIdx.y;

    const int xl = (x8 == 0) ? 0 : x8 - 4;
    const int xr = (x8 == 248) ? 248 : x8 + 8;

    #pragma unroll
    for (int i = 0; i < 4; ++i) {
        const int c = cg * 4 + i;
        const float* base = src + ((long long)c << 16);
        const float* wp = dww + c * 9;
        float acc[8];
        #pragma unroll
        for (int j = 0; j < 8; ++j) acc[j] = 0.f;
        #pragma unroll
        for (int dy = 0; dy < 3; ++dy) {
            const int yy = y + dy - 1;
            const bool vld = (yy >= 0 && yy < IMG);
            const float* row = base + (vld ? yy : y) * IMG;
            const float w0 = vld ? wp[dy * 3 + 0] : 0.f;
            const float w1 = vld ? wp[dy * 3 + 1] : 0.f;
            const float w2 = vld ? wp[dy * 3 + 2] : 0.f;
            const float4 Lq = *(const float4*)(row + xl);
            const float4 M0 = *(const float4*)(row + x8);
            const float4 M1 = *(const float4*)(row + x8 + 4);
            const float4 Rq = *(const float4*)(row + xr);
            float vv[10];
            vv[0] = (x8 == 0) ? 0.f : Lq.w;
            vv[1] = M0.x; vv[2] = M0.y; vv[3] = M0.z; vv[4] = M0.w;
            vv[5] = M1.x; vv[6] = M1.y; vv[7] = M1.z; vv[8] = M1.w;
            vv[9] = (x8 == 248) ? 0.f : Rq.x;
            #pragma unroll
            for (int j = 0; j < 8; ++j)
                acc[j] = fmaf(w0, vv[j], fmaf(w1, vv[j + 1], fmaf(w2, vv[j + 2], acc[j])));
        }
        float4 o0, o1;
        o0.x = acc[0]; o0.y = acc[1]; o0.z = acc[2]; o0.w = acc[3];
        o1.x = acc[4]; o1.y = acc[5]; o1.z = acc[6]; o1.w = acc[7];
        float* drow = dst + ((long long)c << 16) + y * IMG + x8;
        *(float4*)drow = o0;
        *(float4*)(drow + 4) = o1;
    }
}

// ---------------------------------------------------------------------------
// dwconv_vt: depthwise 3x3 on v + FUSED transpose-convert epilogue: writes
// hi/lo bf16 planes in [n][192] layout directly (K4's B format).
// Grid: (256 rows, 6 ch-groups).
// ---------------------------------------------------------------------------
__global__ __launch_bounds__(256) void dwconv_vt(
    const float* __restrict__ src, const float* __restrict__ dww,
    ushort* __restrict__ hi, ushort* __restrict__ lo)
{
    const int t = threadIdx.x;
    const int y  = blockIdx.x;
    const int cg = blockIdx.y;
    const int pxg = t & 31, chq = t >> 5;
    const int x8 = pxg * 8;
    const int c0 = cg * 32 + chq * 4;

    const int xl = (x8 == 0) ? 0 : x8 - 4;
    const int xr = (x8 == 248) ? 248 : x8 + 8;

    float accA[4][8];
    #pragma unroll
    for (int i = 0; i < 4; ++i) {
        const int c = c0 + i;
        const float* base = src + ((long long)c << 16);
        const float* wp = dww + c * 9;
        #pragma unroll
        for (int j = 0; j < 8; ++j) accA[i][j] = 0.f;
        #pragma unroll
        for (int dy = 0; dy < 3; ++dy) {
            const int yy = y + dy - 1;
            const bool vld = (yy >= 0 && yy < IMG);
            const float* row = base + (vld ? yy : y) * IMG;
            const float w0 = vld ? wp[dy * 3 + 0] : 0.f;
            const float w1 = vld ? wp[dy * 3 + 1] : 0.f;
            const float w2 = vld ? wp[dy * 3 + 2] : 0.f;
            const float4 Lq = *(const float4*)(row + xl);
            const float4 M0 = *(const float4*)(row + x8);
            const float4 M1 = *(const float4*)(row + x8 + 4);
            const float4 Rq = *(const float4*)(row + xr);
            float vv[10];
            vv[0] = (x8 == 0) ? 0.f : Lq.w;
            vv[1] = M0.x; vv[2] = M0.y; vv[3] = M0.z; vv[4] = M0.w;
            vv[5] = M1.x; vv[6] = M1.y; vv[7] = M1.z; vv[8] = M1.w;
            vv[9] = (x8 == 248) ? 0.f : Rq.x;
            #pragma unroll
            for (int j = 0; j < 8; ++j)
                accA[i][j] = fmaf(w0, vv[j], fmaf(w1, vv[j + 1], fmaf(w2, vv[j + 2], accA[i][j])));
        }
    }
    const long long nbase = (long long)y * 256 + x8;
    #pragma unroll
    for (int j = 0; j < 8; ++j) {
        ushort h4[4], l4[4];
        #pragma unroll
        for (int i = 0; i < 4; ++i) {
            const float v = accA[i][j];
            h4[i] = f2bf(v);
            l4[i] = f2bf(v - bf2f(h4[i]));
        }
        uint2 H, L;
        H.x = pk2(h4[0], h4[1]); H.y = pk2(h4[2], h4[3]);
        L.x = pk2(l4[0], l4[1]); L.y = pk2(l4[2], l4[3]);
        const long long o = (nbase + j) * 192 + c0;
        *(uint2*)(hi + o) = H;
        *(uint2*)(lo + o) = L;
    }
}

// ---------------------------------------------------------------------------
// gred: G/Sq/Sk partials from post-DW q,k. q,k tiles staged in LDS once
// (coalesced, unique); compute reads LDS (8-lane sharing = broadcast).
// Reduction scratch overlays staging LDS. No atomics.
// ---------------------------------------------------------------------------
__global__ __launch_bounds__(256) void gred(
    const float* __restrict__ q, const float* __restrict__ k, float* __restrict__ Gpart)
{
    __shared__ float smem[8448];          // qs: [0,4224) ks: [4224,8448); stride 132
    float* qs = smem;
    float* ks = smem + 4224;
    const int t = threadIdx.x;
    const int blk = blockIdx.x, h = blockIdx.y;
    const int w = t >> 6, l = t & 63;
    const int cqd = l >> 3, dqd = l & 7;

    float acc[4][4];
    #pragma unroll
    for (int i = 0; i < 4; ++i) { acc[i][0]=0.f; acc[i][1]=0.f; acc[i][2]=0.f; acc[i][3]=0.f; }
    float sq[4] = {0.f,0.f,0.f,0.f}, sk[4] = {0.f,0.f,0.f,0.f};

    const float* qh = q + ((long long)(h * 32) << 16);
    const float* kh = k + ((long long)(h * 32) << 16);

    for (int s = 0; s < 4; ++s) {
        const int n0s = blk * 512 + s * 128;
        #pragma unroll
        for (int i = 0; i < 4; ++i) {
            const int f4 = t + i * 256;
            const int ch = f4 >> 5, n4 = (f4 & 31) * 4;
            const long long go = ((long long)ch << 16) + n0s + n4;
            *(float4*)&qs[ch * 132 + n4] = *(const float4*)(qh + go);
            *(float4*)&ks[ch * 132 + n4] = *(const float4*)(kh + go);
        }
        __syncthreads();
        const int nb = w * 32;
        #pragma unroll
        for (int it = 0; it < 8; ++it) {
            const int n = nb + it * 4;
            float4 qa[4], kb[4];
            #pragma unroll
            for (int i = 0; i < 4; ++i) qa[i] = *(const float4*)&qs[(cqd * 4 + i) * 132 + n];
            #pragma unroll
            for (int j = 0; j < 4; ++j) kb[j] = *(const float4*)&ks[(dqd * 4 + j) * 132 + n];
            #pragma unroll
            for (int i = 0; i < 4; ++i) {
                #pragma unroll
                for (int j = 0; j < 4; ++j) {
                    acc[i][j] = fmaf(qa[i].x, kb[j].x, acc[i][j]);
                    acc[i][j] = fmaf(qa[i].y, kb[j].y, acc[i][j]);
                    acc[i][j] = fmaf(qa[i].z, kb[j].z, acc[i][j]);
                    acc[i][j] = fmaf(qa[i].w, kb[j].w, acc[i][j]);
                }
            }
            if (dqd == 0) {
                #pragma unroll
                for (int i = 0; i < 4; ++i) {
                    sq[i] = fmaf(qa[i].x, qa[i].x, sq[i]);
                    sq[i] = fmaf(qa[i].y, qa[i].y, sq[i]);
                    sq[i] = fmaf(qa[i].z, qa[i].z, sq[i]);
                    sq[i] = fmaf(qa[i].w, qa[i].w, sq[i]);
                }
            }
            if (cqd == 0) {
                #pragma unroll
                for (int j = 0; j < 4; ++j) {
                    sk[j] = fmaf(kb[j].x, kb[j].x, sk[j]);
                    sk[j] = fmaf(kb[j].y, kb[j].y, sk[j]);
                    sk[j] = fmaf(kb[j].z, kb[j].z, sk[j]);
                    sk[j] = fmaf(kb[j].w, kb[j].w, sk[j]);
                }
            }
        }
        __syncthreads();
    }

    float* red  = smem;                   // overlays (staging dead post-barrier)
    float* red2 = smem + 4096;
    #pragma unroll
    for (int i = 0; i < 4; ++i) {
        #pragma unroll
        for (int j = 0; j < 4; ++j)
            red[w * 1024 + (cqd * 4 + i) * 32 + dqd * 4 + j] = acc[i][j];
    }
    if (dqd == 0) {
        #pragma unroll
        for (int i = 0; i < 4; ++i) red2[w * 32 + cqd * 4 + i] = sq[i];
    }
    if (cqd == 0) {
        #pragma unroll
        for (int j = 0; j < 4; ++j) red2[128 + w * 32 + dqd * 4 + j] = sk[j];
    }
    __syncthreads();

    float* Gp = Gpart + (long long)(h * 128 + blk) * 1088;
    #pragma unroll
    for (int i = 0; i < 4; ++i) {
        int slot = t + i * 256;
        Gp[slot] = red[slot] + red[1024 + slot] + red[2048 + slot] + red[3072 + slot];
    }
    if (t < 32) {
        Gp[1024 + t] = red2[t] + red2[32 + t] + red2[64 + t] + red2[96 + t];
    } else if (t < 64) {
        int c = t - 32;
        Gp[1056 + c] = red2[128 + c] + red2[160 + c] + red2[192 + c] + red2[224 + c];
    }
}

__global__ void reduce_g(const float* __restrict__ Gpart, float* __restrict__ G,
                         float* __restrict__ Sq, float* __restrict__ Sk, int bh0)
{
    const int h = blockIdx.x, t = threadIdx.x;
    const float* Gp = Gpart + (long long)h * 128 * 1088;
    const int bh = bh0 + h;
    #pragma unroll
    for (int i = 0; i < 5; ++i) {
        int slot = t + i * 256;
        if (slot >= 1088) break;
        float s = 0.f;
        for (int tl = 0; tl < 128; ++tl) s += Gp[(long long)tl * 1088 + slot];
        if (slot < 1024)      G[(long long)bh * 1024 + slot] = s;
        else if (slot < 1056) Sq[bh * 32 + (slot - 1024)] = s;
        else                  Sk[bh * 32 + (slot - 1056)] = s;
    }
}

__global__ void attn_small(const float* __restrict__ G, const float* __restrict__ Sq,
                           const float* __restrict__ Sk, const float* __restrict__ temp,
                           const float* __restrict__ attn1, float* __restrict__ A)
{
    const int h = blockIdx.x, b = blockIdx.y, c = threadIdx.x;
    const int bh = b * 6 + h;
    const float* g = G + ((long long)bh * 32 + c) * 32;
    const float nq = fmaxf(sqrtf(Sq[bh * 32 + c]), 1e-12f);
    const float T  = temp[h];
    const float a1 = attn1[0];

    float a[32];
    #pragma unroll
    for (int d = 0; d < 32; ++d) {
        float nk = fmaxf(sqrtf(Sk[bh * 32 + d]), 1e-12f);
        a[d] = g[d] / (nq * nk) * T;
    }
    unsigned mask = 0u;
    float m = 0.f, kth = 0.f;
    for (int it = 0; it < 16; ++it) {
        float best = -3.4e38f; int bi = 0;
        #pragma unroll
        for (int d = 0; d < 32; ++d) {
            bool avail = ((mask >> d) & 1u) == 0u;
            if (avail && a[d] > best) { best = a[d]; bi = d; }
        }
        mask |= (1u << bi);
        if (it == 0) m = best;
        kth = best;
    }
    float denom = 0.f;
    #pragma unroll
    for (int d = 0; d < 32; ++d) if (a[d] >= kth) denom += expf(a[d] - m);
    const float inv = a1 / denom;
    float* Ar = A + ((long long)bh * 32 + c) * 32;
    #pragma unroll
    for (int d = 0; d < 32; ++d) Ar[d] = (a[d] >= kth) ? expf(a[d] - m) * inv : 0.f;
}

__global__ void make_m(const float* __restrict__ proj_w, const float* __restrict__ A,
                       float* __restrict__ M)
{
    const int o = blockIdx.x, b = blockIdx.y, j = threadIdx.x;
    const int hd = j >> 5, d = j & 31;
    const float* pw = proj_w + o * 192 + hd * 32;
    const float* Ah = A + ((long long)(b * 6 + hd) * 32) * 32 + d;
    float s = 0.f;
    #pragma unroll
    for (int cq = 0; cq < 32; ++cq) s = fmaf(pw[cq], Ah[cq * 32], s);
    M[((long long)(b * 192 + o)) * 192 + j] = s;
}

// ---------------------------------------------------------------------------
extern "C" void kernel_launch(void* const* d_in, const int* in_sizes, int n_in,
                              void* d_out, int out_size, void* d_ws, size_t ws_size,
                              hipStream_t stream)
{
    const float* x      = (const float*)d_in[0];
    const float* qkv_w  = (const float*)d_in[1];
    const float* dww    = (const float*)d_in[2];
    const float* proj_w = (const float*)d_in[3];
    const float* temp   = (const float*)d_in[4];
    const float* attn1  = (const float*)d_in[5];
    float* out = (float*)d_out;
    float* wsf = (float*)d_ws;

    // ws layout (floats) -- round-13 proven layout, 101,059,584 bytes
    float* G   = wsf;                 // 12,288
    float* Sq  = G + 12288;           // 384
    float* Sk  = Sq + 384;            // 384
    float* A   = Sk + 384;            // 12,288
    float* Mm  = A + 12288;           // 73,728
    float* buf = Mm + 73728;          // 96 MiB

    const long long PL = 12582912LL;  // floats per 48 MiB region
    float* W1 = buf;
    float* W2 = buf + PL;
    float* R1 = out;                  // batch-0 out region
    float* R2 = out + PL;             // batch-1 out region

    ushort* R1H = (ushort*)R1; ushort* R1L = R1H + PL;
    ushort* W1H = (ushort*)W1; ushort* W1L = W1H + PL;

    // ---- Phase S, b=0
    transp_conv<<<dim3(1024, 6), 256, 0, stream>>>(x, R1H, R1L);
    gemm_mfma<<<dim3(1536), 256, 0, stream>>>(qkv_w, 0, 6, R1H, R1L, buf);
    dwconv8<<<dim3(32, 48), 256, 0, stream>>>(W1, dww, R2);            // qpost
    dwconv8<<<dim3(32, 48), 256, 0, stream>>>(W2, dww + 192 * 9, W1);  // kpost
    gred<<<dim3(128, 6), 256, 0, stream>>>(R2, W1, W2);
    reduce_g<<<dim3(6, 1), 256, 0, stream>>>(W2, G, Sq, Sk, 0);

    // ---- Phase S, b=1: Xt(x1)@R1 stays ALIVE for the v-path
    transp_conv<<<dim3(1024, 6), 256, 0, stream>>>(x + PL, R1H, R1L);
    gemm_mfma<<<dim3(1536), 256, 0, stream>>>(qkv_w, 0, 6, R1H, R1L, buf);
    dwconv8<<<dim3(32, 48), 256, 0, stream>>>(W1, dww, R2);
    dwconv8<<<dim3(32, 48), 256, 0, stream>>>(W2, dww + 192 * 9, W1);
    gred<<<dim3(128, 6), 256, 0, stream>>>(R2, W1, W2);
    reduce_g<<<dim3(6, 1), 256, 0, stream>>>(W2, G, Sq, Sk, 6);

    // ---- Phase B: tiny attention matrices + fused projection matrices
    attn_small<<<dim3(6, 2), 32, 0, stream>>>(G, Sq, Sk, temp, attn1, A);
    make_m<<<dim3(192, 2), 192, 0, stream>>>(proj_w, A, Mm);

    // ---- V+K4, b=1 (reuses Xt(x1)@R1): K1v->W2 ; dwconv_vt: W2 -> W1 planes ; K4->R2
    gemm_mfma<<<dim3(768), 256, 0, stream>>>(qkv_w, 384, 3, R1H, R1L, W2);
    dwconv_vt<<<dim3(256, 6), 256, 0, stream>>>(W2, dww + 384 * 9, W1H, W1L);
    gemm_mfma<<<dim3(768), 256, 0, stream>>>(Mm + 36864, 0, 3, W1H, W1L, R2);

    // ---- V+K4, b=0: Xt(x0)@R1 ; K1v->W2 ; dwconv_vt: W2 -> W1 planes ; K4->R1 (final)
    transp_conv<<<dim3(1024, 6), 256, 0, stream>>>(x, R1H, R1L);
    gemm_mfma<<<dim3(768), 256, 0, stream>>>(qkv_w, 384, 3, R1H, R1L, W2);
    dwconv_vt<<<dim3(256, 6), 256, 0, stream>>>(W2, dww + 384 * 9, W1H, W1L);
    gemm_mfma<<<dim3(768), 256, 0, stream>>>(Mm, 0, 3, W1H, W1L, R1);
}

// Round 17
// 540.879 us; speedup vs baseline: 1.3079x; 1.1116x over previous
//
#include <hip/hip_runtime.h>
#include <math.h>

#define N_SP 65536   // h*w
#define IMG  256

typedef __attribute__((ext_vector_type(8))) short s16x8;
typedef __attribute__((ext_vector_type(4))) float f32x4;

// RNE fp32->bf16 (bit version, deterministic) and back
__device__ inline ushort f2bf(float f) {
    uint u = __float_as_uint(f);
    return (ushort)((u + 0x7FFFu + ((u >> 16) & 1u)) >> 16);
}
__device__ inline float bf2f(ushort h) { return __uint_as_float(((uint)h) << 16); }
__device__ inline uint pk2(ushort a, ushort b) { return (uint)a | ((uint)b << 16); }

// Direct HBM->LDS DMA, 16B per lane. LDS dest = wave-uniform base + lane*16.
__device__ __forceinline__ void load_lds16f(const float* g, float* l) {
    __builtin_amdgcn_global_load_lds(
        (const __attribute__((address_space(1))) void*)g,
        (__attribute__((address_space(3))) void*)l, 16, 0, 0);
}

// ---------------------------------------------------------------------------
// gemm_xf: C[m][n] = sum_k Wf[wrow0+m][k] * X[k][n], K=192, split-bf16
// (C = Whi*Xhi + Whi*Xlo + Wlo*Xhi; lo*lo dropped, ~1e-5 rel).
// ROUND-17: X read DIRECTLY in fp32 [k][N_SP] layout -- the [n][192] bf16
// plane intermediate (transp_conv / dwconv_vt epilogue) is eliminated.
//  - X staged as fp32 32x256 tile via global_load_lds (1KB rows, linear LDS);
//  - B-fragment: gather 8 fp32 from the LDS column, convert/split to hi/lo in
//    regs (round-15 proved conversion VALU is off the critical path; round-9
//    proved the <=4-way column-gather conflicts are too). Same k-slot map for
//    A and B => HW k-permutation cancels. Bitwise-same math as plane path.
//  - W converted in-kernel as before. Round-14 dbuf / round-10 reg-prefetch
//    regressed -- do not revisit.
// ROUND-16 T1 swizzle kept: flat grid nm*256; d: r=d&7,q=d>>3, m=(q%nm),
// n=(q/nm)*8+r -> same-n m-blocks share an XCD, temporally adjacent.
// C/D (m89): col=lane&15, row=(lane>>4)*4+j.
// ---------------------------------------------------------------------------
__global__ __launch_bounds__(256) void gemm_xf(
    const float* __restrict__ Wf, int wrow0, int nm,
    const float* __restrict__ X, float* __restrict__ C)
{
    __shared__ ushort WsH[64][40], WsL[64][40];
    __shared__ float Xs[32 * 256];          // [k][n] linear, 1KB rows
    const int t  = threadIdx.x;
    const int wv = t >> 6, l = t & 63;
    const int lc = l & 15, lg = l >> 4;
    const int d = blockIdx.x;
    const int r = d & 7, q = d >> 3;
    const int m0 = (q % nm) * 64;
    const long long n0 = (long long)((q / nm) * 8 + r) * 256;

    f32x4 acc[4][4];
    #pragma unroll
    for (int i = 0; i < 4; ++i)
        #pragma unroll
        for (int j = 0; j < 4; ++j) acc[i][j] = (f32x4)(0.f);

    const int ar = t >> 2, ak = (t & 3) * 8;
    const int rXk = wv * 8;                 // wave stages X rows [wv*8, wv*8+8)

    for (int kc = 0; kc < 192; kc += 32) {
        // 1) X tile DMA: 8 rows/wave, 1KB each (lane l -> +l*16B)
        #pragma unroll
        for (int i = 0; i < 8; ++i) {
            load_lds16f(X + (long long)(kc + rXk + i) * N_SP + n0 + l * 4,
                        &Xs[(rXk + i) * 256]);
        }
        // 2) W tile: fp32 load, hi/lo split, ds_write (overlaps DMA)
        {
            const float* wp = Wf + (long long)(wrow0 + m0 + ar) * 192 + kc + ak;
            const float4 a0 = *(const float4*)wp;
            const float4 a1 = *(const float4*)(wp + 4);
            const float v[8] = {a0.x, a0.y, a0.z, a0.w, a1.x, a1.y, a1.z, a1.w};
            ushort h[8], lo_[8];
            #pragma unroll
            for (int j = 0; j < 8; ++j) { h[j] = f2bf(v[j]); lo_[j] = f2bf(v[j] - bf2f(h[j])); }
            uint4 H, L;
            H.x = pk2(h[0],h[1]); H.y = pk2(h[2],h[3]); H.z = pk2(h[4],h[5]); H.w = pk2(h[6],h[7]);
            L.x = pk2(lo_[0],lo_[1]); L.y = pk2(lo_[2],lo_[3]); L.z = pk2(lo_[4],lo_[5]); L.w = pk2(lo_[6],lo_[7]);
            *(uint4*)&WsH[ar][ak] = H;
            *(uint4*)&WsL[ar][ak] = L;
        }
        __syncthreads();

        s16x8 ah[4], al[4];
        #pragma unroll
        for (int mf = 0; mf < 4; ++mf) {
            ah[mf] = *(const s16x8*)&WsH[mf * 16 + lc][lg * 8];
            al[mf] = *(const s16x8*)&WsL[mf * 16 + lc][lg * 8];
        }
        #pragma unroll
        for (int nf = 0; nf < 4; ++nf) {
            const int nr = wv * 64 + nf * 16 + lc;
            s16x8 bh, bl;
            #pragma unroll
            for (int s = 0; s < 8; ++s) {
                const float xv = Xs[(lg * 8 + s) * 256 + nr];
                const ushort hh = f2bf(xv);
                bh[s] = (short)hh;
                bl[s] = (short)f2bf(xv - bf2f(hh));
            }
            #pragma unroll
            for (int mf = 0; mf < 4; ++mf) {
                acc[mf][nf] = __builtin_amdgcn_mfma_f32_16x16x32_bf16(ah[mf], bh, acc[mf][nf], 0, 0, 0);
                acc[mf][nf] = __builtin_amdgcn_mfma_f32_16x16x32_bf16(ah[mf], bl, acc[mf][nf], 0, 0, 0);
                acc[mf][nf] = __builtin_amdgcn_mfma_f32_16x16x32_bf16(al[mf], bh, acc[mf][nf], 0, 0, 0);
            }
        }
        __syncthreads();
    }

    #pragma unroll
    for (int mf = 0; mf < 4; ++mf)
        #pragma unroll
        for (int nf = 0; nf < 4; ++nf) {
            const long long nn = n0 + wv * 64 + nf * 16 + lc;
            #pragma unroll
            for (int j = 0; j < 4; ++j)
                C[(long long)(m0 + mf * 16 + lg * 4 + j) * N_SP + nn] = acc[mf][nf][j];
        }
}

// ---------------------------------------------------------------------------
// dwconv8: depthwise 3x3, register-shift, 8 px x 4 channels per thread.
// fp32 [c][n] in/out (q, k, and now v too -- dwconv_vt's transpose epilogue
// was 3.5x its traffic floor from scattered 8B writes; gone in round-17).
// Halo via clamped loads + zeroed weights.
// ---------------------------------------------------------------------------
__global__ __launch_bounds__(256) void dwconv8(
    const float* __restrict__ src, const float* __restrict__ dww, float* __restrict__ dst)
{
    const int t = threadIdx.x;
    const int s = blockIdx.x * 256 + t;
    const int y = s >> 5;
    const int x8 = (s & 31) * 8;
    const int cg = blockIdx.y;

    const int xl = (x8 == 0) ? 0 : x8 - 4;
    const int xr = (x8 == 248) ? 248 : x8 + 8;

    #pragma unroll
    for (int i = 0; i < 4; ++i) {
        const int c = cg * 4 + i;
        const float* base = src + ((long long)c << 16);
        const float* wp = dww + c * 9;
        float acc[8];
        #pragma unroll
        for (int j = 0; j < 8; ++j) acc[j] = 0.f;
        #pragma unroll
        for (int dy = 0; dy < 3; ++dy) {
            const int yy = y + dy - 1;
            const bool vld = (yy >= 0 && yy < IMG);
            const float* row = base + (vld ? yy : y) * IMG;
            const float w0 = vld ? wp[dy * 3 + 0] : 0.f;
            const float w1 = vld ? wp[dy * 3 + 1] : 0.f;
            const float w2 = vld ? wp[dy * 3 + 2] : 0.f;
            const float4 Lq = *(const float4*)(row + xl);
            const float4 M0 = *(const float4*)(row + x8);
            const float4 M1 = *(const float4*)(row + x8 + 4);
            const float4 Rq = *(const float4*)(row + xr);
            float vv[10];
            vv[0] = (x8 == 0) ? 0.f : Lq.w;
            vv[1] = M0.x; vv[2] = M0.y; vv[3] = M0.z; vv[4] = M0.w;
            vv[5] = M1.x; vv[6] = M1.y; vv[7] = M1.z; vv[8] = M1.w;
            vv[9] = (x8 == 248) ? 0.f : Rq.x;
            #pragma unroll
            for (int j = 0; j < 8; ++j)
                acc[j] = fmaf(w0, vv[j], fmaf(w1, vv[j + 1], fmaf(w2, vv[j + 2], acc[j])));
        }
        float4 o0, o1;
        o0.x = acc[0]; o0.y = acc[1]; o0.z = acc[2]; o0.w = acc[3];
        o1.x = acc[4]; o1.y = acc[5]; o1.z = acc[6]; o1.w = acc[7];
        float* drow = dst + ((long long)c << 16) + y * IMG + x8;
        *(float4*)drow = o0;
        *(float4*)(drow + 4) = o1;
    }
}

// ---------------------------------------------------------------------------
// gred: G/Sq/Sk partials from post-DW q,k. q,k tiles staged in LDS once
// (coalesced, unique); compute reads LDS (8-lane sharing = broadcast).
// Reduction scratch overlays staging LDS. No atomics.
// ---------------------------------------------------------------------------
__global__ __launch_bounds__(256) void gred(
    const float* __restrict__ q, const float* __restrict__ k, float* __restrict__ Gpart)
{
    __shared__ float smem[8448];          // qs: [0,4224) ks: [4224,8448); stride 132
    float* qs = smem;
    float* ks = smem + 4224;
    const int t = threadIdx.x;
    const int blk = blockIdx.x, h = blockIdx.y;
    const int w = t >> 6, l = t & 63;
    const int cqd = l >> 3, dqd = l & 7;

    float acc[4][4];
    #pragma unroll
    for (int i = 0; i < 4; ++i) { acc[i][0]=0.f; acc[i][1]=0.f; acc[i][2]=0.f; acc[i][3]=0.f; }
    float sq[4] = {0.f,0.f,0.f,0.f}, sk[4] = {0.f,0.f,0.f,0.f};

    const float* qh = q + ((long long)(h * 32) << 16);
    const float* kh = k + ((long long)(h * 32) << 16);

    for (int s = 0; s < 4; ++s) {
        const int n0s = blk * 512 + s * 128;
        #pragma unroll
        for (int i = 0; i < 4; ++i) {
            const int f4 = t + i * 256;
            const int ch = f4 >> 5, n4 = (f4 & 31) * 4;
            const long long go = ((long long)ch << 16) + n0s + n4;
            *(float4*)&qs[ch * 132 + n4] = *(const float4*)(qh + go);
            *(float4*)&ks[ch * 132 + n4] = *(const float4*)(kh + go);
        }
        __syncthreads();
        const int nb = w * 32;
        #pragma unroll
        for (int it = 0; it < 8; ++it) {
            const int n = nb + it * 4;
            float4 qa[4], kb[4];
            #pragma unroll
            for (int i = 0; i < 4; ++i) qa[i] = *(const float4*)&qs[(cqd * 4 + i) * 132 + n];
            #pragma unroll
            for (int j = 0; j < 4; ++j) kb[j] = *(const float4*)&ks[(dqd * 4 + j) * 132 + n];
            #pragma unroll
            for (int i = 0; i < 4; ++i) {
                #pragma unroll
                for (int j = 0; j < 4; ++j) {
                    acc[i][j] = fmaf(qa[i].x, kb[j].x, acc[i][j]);
                    acc[i][j] = fmaf(qa[i].y, kb[j].y, acc[i][j]);
                    acc[i][j] = fmaf(qa[i].z, kb[j].z, acc[i][j]);
                    acc[i][j] = fmaf(qa[i].w, kb[j].w, acc[i][j]);
                }
            }
            if (dqd == 0) {
                #pragma unroll
                for (int i = 0; i < 4; ++i) {
                    sq[i] = fmaf(qa[i].x, qa[i].x, sq[i]);
                    sq[i] = fmaf(qa[i].y, qa[i].y, sq[i]);
                    sq[i] = fmaf(qa[i].z, qa[i].z, sq[i]);
                    sq[i] = fmaf(qa[i].w, qa[i].w, sq[i]);
                }
            }
            if (cqd == 0) {
                #pragma unroll
                for (int j = 0; j < 4; ++j) {
                    sk[j] = fmaf(kb[j].x, kb[j].x, sk[j]);
                    sk[j] = fmaf(kb[j].y, kb[j].y, sk[j]);
                    sk[j] = fmaf(kb[j].z, kb[j].z, sk[j]);
                    sk[j] = fmaf(kb[j].w, kb[j].w, sk[j]);
                }
            }
        }
        __syncthreads();
    }

    float* red  = smem;                   // overlays (staging dead post-barrier)
    float* red2 = smem + 4096;
    #pragma unroll
    for (int i = 0; i < 4; ++i) {
        #pragma unroll
        for (int j = 0; j < 4; ++j)
            red[w * 1024 + (cqd * 4 + i) * 32 + dqd * 4 + j] = acc[i][j];
    }
    if (dqd == 0) {
        #pragma unroll
        for (int i = 0; i < 4; ++i) red2[w * 32 + cqd * 4 + i] = sq[i];
    }
    if (cqd == 0) {
        #pragma unroll
        for (int j = 0; j < 4; ++j) red2[128 + w * 32 + dqd * 4 + j] = sk[j];
    }
    __syncthreads();

    float* Gp = Gpart + (long long)(h * 128 + blk) * 1088;
    #pragma unroll
    for (int i = 0; i < 4; ++i) {
        int slot = t + i * 256;
        Gp[slot] = red[slot] + red[1024 + slot] + red[2048 + slot] + red[3072 + slot];
    }
    if (t < 32) {
        Gp[1024 + t] = red2[t] + red2[32 + t] + red2[64 + t] + red2[96 + t];
    } else if (t < 64) {
        int c = t - 32;
        Gp[1056 + c] = red2[128 + c] + red2[160 + c] + red2[192 + c] + red2[224 + c];
    }
}

__global__ void reduce_g(const float* __restrict__ Gpart, float* __restrict__ G,
                         float* __restrict__ Sq, float* __restrict__ Sk, int bh0)
{
    const int h = blockIdx.x, t = threadIdx.x;
    const float* Gp = Gpart + (long long)h * 128 * 1088;
    const int bh = bh0 + h;
    #pragma unroll
    for (int i = 0; i < 5; ++i) {
        int slot = t + i * 256;
        if (slot >= 1088) break;
        float s = 0.f;
        for (int tl = 0; tl < 128; ++tl) s += Gp[(long long)tl * 1088 + slot];
        if (slot < 1024)      G[(long long)bh * 1024 + slot] = s;
        else if (slot < 1056) Sq[bh * 32 + (slot - 1024)] = s;
        else                  Sk[bh * 32 + (slot - 1056)] = s;
    }
}

__global__ void attn_small(const float* __restrict__ G, const float* __restrict__ Sq,
                           const float* __restrict__ Sk, const float* __restrict__ temp,
                           const float* __restrict__ attn1, float* __restrict__ A)
{
    const int h = blockIdx.x, b = blockIdx.y, c = threadIdx.x;
    const int bh = b * 6 + h;
    const float* g = G + ((long long)bh * 32 + c) * 32;
    const float nq = fmaxf(sqrtf(Sq[bh * 32 + c]), 1e-12f);
    const float T  = temp[h];
    const float a1 = attn1[0];

    float a[32];
    #pragma unroll
    for (int d = 0; d < 32; ++d) {
        float nk = fmaxf(sqrtf(Sk[bh * 32 + d]), 1e-12f);
        a[d] = g[d] / (nq * nk) * T;
    }
    unsigned mask = 0u;
    float m = 0.f, kth = 0.f;
    for (int it = 0; it < 16; ++it) {
        float best = -3.4e38f; int bi = 0;
        #pragma unroll
        for (int d = 0; d < 32; ++d) {
            bool avail = ((mask >> d) & 1u) == 0u;
            if (avail && a[d] > best) { best = a[d]; bi = d; }
        }
        mask |= (1u << bi);
        if (it == 0) m = best;
        kth = best;
    }
    float denom = 0.f;
    #pragma unroll
    for (int d = 0; d < 32; ++d) if (a[d] >= kth) denom += expf(a[d] - m);
    const float inv = a1 / denom;
    float* Ar = A + ((long long)bh * 32 + c) * 32;
    #pragma unroll
    for (int d = 0; d < 32; ++d) Ar[d] = (a[d] >= kth) ? expf(a[d] - m) * inv : 0.f;
}

__global__ void make_m(const float* __restrict__ proj_w, const float* __restrict__ A,
                       float* __restrict__ M)
{
    const int o = blockIdx.x, b = blockIdx.y, j = threadIdx.x;
    const int hd = j >> 5, d = j & 31;
    const float* pw = proj_w + o * 192 + hd * 32;
    const float* Ah = A + ((long long)(b * 6 + hd) * 32) * 32 + d;
    float s = 0.f;
    #pragma unroll
    for (int cq = 0; cq < 32; ++cq) s = fmaf(pw[cq], Ah[cq * 32], s);
    M[((long long)(b * 192 + o)) * 192 + j] = s;
}

// ---------------------------------------------------------------------------
extern "C" void kernel_launch(void* const* d_in, const int* in_sizes, int n_in,
                              void* d_out, int out_size, void* d_ws, size_t ws_size,
                              hipStream_t stream)
{
    const float* x      = (const float*)d_in[0];
    const float* qkv_w  = (const float*)d_in[1];
    const float* dww    = (const float*)d_in[2];
    const float* proj_w = (const float*)d_in[3];
    const float* temp   = (const float*)d_in[4];
    const float* attn1  = (const float*)d_in[5];
    float* out = (float*)d_out;
    float* wsf = (float*)d_ws;

    // ws layout (floats) -- proven-safe 101,059,584 bytes total
    float* G   = wsf;                 // 12,288
    float* Sq  = G + 12288;           // 384
    float* Sk  = Sq + 384;            // 384
    float* A   = Sk + 384;            // 12,288
    float* Mm  = A + 12288;           // 73,728
    float* buf = Mm + 73728;          // 96 MiB (= 384 x 65536 floats exactly)

    const long long PL = 12582912LL;  // floats per 48 MiB region
    float* W1 = buf;                  // buf rows 0-191
    float* W2 = buf + PL;             // buf rows 192-383
    float* R1 = out;                  // batch-0 out region (scratch until final)
    float* R2 = out + PL;             // batch-1 out region

    // ---- Phase S (attention statistics) per batch: q,k never persist
    for (int b = 0; b < 2; ++b) {
        const float* xb = x + (long long)b * PL;
        gemm_xf<<<dim3(1536), 256, 0, stream>>>(qkv_w, 0, 6, xb, buf);   // q@W1,k@W2
        dwconv8<<<dim3(32, 48), 256, 0, stream>>>(W1, dww, R1);          // qpost
        dwconv8<<<dim3(32, 48), 256, 0, stream>>>(W2, dww + 192 * 9, R2);// kpost
        gred<<<dim3(128, 6), 256, 0, stream>>>(R1, R2, W1);              // Gpart@W1
        reduce_g<<<dim3(6, 1), 256, 0, stream>>>(W1, G, Sq, Sk, b * 6);
    }

    // ---- Phase B: tiny attention matrices + fused projection matrices
    attn_small<<<dim3(6, 2), 32, 0, stream>>>(G, Sq, Sk, temp, attn1, A);
    make_m<<<dim3(192, 2), 192, 0, stream>>>(proj_w, A, Mm);

    // ---- Phase V+K4 per batch: K1v -> W1 ; dw -> W2 ; out_b = M_b @ vpost
    for (int b = 0; b < 2; ++b) {
        const float* xb = x + (long long)b * PL;
        float* outb = out + (long long)b * PL;
        gemm_xf<<<dim3(768), 256, 0, stream>>>(qkv_w, 384, 3, xb, W1);
        dwconv8<<<dim3(32, 48), 256, 0, stream>>>(W1, dww + 384 * 9, W2);
        gemm_xf<<<dim3(768), 256, 0, stream>>>(Mm + (long long)b * 36864, 0, 3, W2, outb);
    }
}